// Round 12
// baseline (200.433 us; speedup 1.0000x reference)
//
#include <hip/hip_runtime.h>

// HeavilyCompressedAttention on MI355X (gfx950). R12:
//  - k_gemm_qkv128: 128x128 tile, BK=64, R9's pipelined 1-barrier loop,
//    ^(r&7) swizzle, 65 KB LDS -> 2 blocks/CU, grid 770 (768 XCD-swizzled
//    + ck/cv blocks). Epilogues from R5 (verified 128-col norm/rope etc).
//  - k_pre / k_attn / k_gemm_out identical to R11 (verified).

typedef unsigned short u16;
typedef __attribute__((ext_vector_type(8))) short short8;
typedef __attribute__((ext_vector_type(4))) float f32x4;

#define S_LEN 2048
#define HIDN  2048
#define NHEAD 16
#define HDIM  128
#define NCHNK 128
#define NKT   32                      // K tiles of 64
#define SCALE 0.08838834764831845f   // 1/sqrt(128)

__device__ __forceinline__ float bf2f(u16 h) {
  return __uint_as_float(((unsigned)h) << 16);
}
__device__ __forceinline__ u16 f2bf(float f) {
  unsigned u = __float_as_uint(f);
  unsigned r = (u + 0x7fffu + ((u >> 16) & 1u)) >> 16;
  return (u16)r;
}

typedef __attribute__((address_space(3))) unsigned int lds_uint;
typedef __attribute__((address_space(1))) unsigned int glb_uint;
__device__ __forceinline__ void gl_lds16(const void* g, void* l) {
  __builtin_amdgcn_global_load_lds((glb_uint*)(unsigned long long)g,
                                   (lds_uint*)(unsigned)(unsigned long long)l,
                                   16, 0, 0);
}

// ---------------- fused preprocessing: grid (64,64,6), block (32,8)
__global__ __launch_bounds__(256) void k_pre(
    const float* __restrict__ Wq, const float* __restrict__ Wlk, const float* __restrict__ Wlv,
    const float* __restrict__ Wo, const float* __restrict__ hs,
    const float* __restrict__ Wc, const float* __restrict__ bc,
    const float* __restrict__ Wk, const float* __restrict__ Wv,
    u16* __restrict__ Wt3, u16* __restrict__ Wt_o, u16* __restrict__ hs_bf,
    float* __restrict__ rope_c, float* __restrict__ rope_s,
    u16* __restrict__ entries_bf, u16* __restrict__ Wkv_t) {
  __shared__ float tile[32][33];
  int z = blockIdx.z;
  int tx = threadIdx.x, ty = threadIdx.y;
  int tid = ty * 32 + tx;
  if (z < 4) {
    const float* src = (z == 0) ? Wq : (z == 1) ? Wlk : (z == 2) ? Wlv : Wo;
    u16* dst = (z < 3) ? (Wt3 + (size_t)z * HIDN * HIDN) : Wt_o;
    int k0 = blockIdx.x * 32, n0 = blockIdx.y * 32;
    #pragma unroll
    for (int i = 0; i < 32; i += 8)
      tile[ty + i][tx] = src[(size_t)(k0 + ty + i) * HIDN + (n0 + tx)];
    __syncthreads();
    #pragma unroll
    for (int i = 0; i < 32; i += 8)
      dst[(size_t)(n0 + ty + i) * HIDN + (k0 + tx)] = f2bf(tile[tx][ty + i]);
    return;
  }
  int bid = blockIdx.y * 64 + blockIdx.x;
  if (z == 4) {   // cast_hs
    size_t i4 = ((size_t)bid * 256 + tid) * 4;
    float4 v = *(const float4*)&hs[i4];
    ushort4 o;
    o.x = f2bf(v.x); o.y = f2bf(v.y); o.z = f2bf(v.z); o.w = f2bf(v.w);
    *(ushort4*)&hs_bf[i4] = o;
    return;
  }
  // z == 5
  if (bid < 256) {   // rope table
    int i = bid * 256 + tid;
    int pos = i >> 5, f = i & 31;
    float inv = __expf(-(float)f * (9.210340371976184f / 32.0f));
    float ang = (float)pos * inv;
    rope_c[i] = cosf(ang);
    rope_s[i] = sinf(ang);
    return;
  }
  if (bid < 384) {   // chunk_we, chunk c = bid-256
    __shared__ float red[16][17];
    __shared__ float wgt[16];
    int c = bid - 256;
    int row = tid >> 4, seg = tid & 15;
    const float* hrow = hs + ((size_t)c * 16 + row) * HIDN;
    float p = 0.f;
    #pragma unroll 8
    for (int k = seg * 128; k < seg * 128 + 128; k += 4) {
      float4 hv = *(const float4*)&hrow[k];
      float4 wv = *(const float4*)&Wc[k];
      p += hv.x * wv.x + hv.y * wv.y + hv.z * wv.z + hv.w * wv.w;
    }
    red[row][seg] = p;
    __syncthreads();
    if (tid < 16) {
      float lg = 0.f;
      #pragma unroll
      for (int j = 0; j < 16; ++j) lg += red[tid][j];
      lg += bc[0];
      float m = lg;
      #pragma unroll
      for (int msk = 1; msk <= 8; msk <<= 1) m = fmaxf(m, __shfl_xor(m, msk));
      float ev = __expf(lg - m);
      float sum = ev;
      #pragma unroll
      for (int msk = 1; msk <= 8; msk <<= 1) sum += __shfl_xor(sum, msk);
      wgt[tid] = ev / sum;
    }
    __syncthreads();
    #pragma unroll
    for (int j = 0; j < 8; ++j) {
      int hb = tid + j * 256;
      float acc = 0.f;
      #pragma unroll
      for (int r = 0; r < 16; ++r)
        acc += wgt[r] * hs[((size_t)c * 16 + r) * HIDN + hb];
      entries_bf[(size_t)c * HIDN + hb] = f2bf(acc);
    }
    return;
  }
  if (bid < 896) {   // transpose_w
    int idx = bid - 384;
    int zw = idx >> 8, byw = (idx >> 6) & 3, bxw = idx & 63;
    const float* src = zw ? Wv : Wk;
    u16* dst = Wkv_t + (size_t)zw * HDIM * 2048;
    int k0 = bxw * 32, n0 = byw * 32;
    #pragma unroll
    for (int i = 0; i < 32; i += 8)
      tile[ty + i][tx] = src[(size_t)(k0 + ty + i) * HDIM + (n0 + tx)];
    __syncthreads();
    #pragma unroll
    for (int i = 0; i < 32; i += 8)
      dst[(size_t)(n0 + ty + i) * 2048 + (k0 + tx)] = f2bf(tile[tx][ty + i]);
  }
}

// ---------------- 128x128 pipelined GEMM for q/lk/lv (+ck/cv blocks 768/769)
__global__ __launch_bounds__(256) void k_gemm_qkv128(
    const u16* __restrict__ A, const u16* __restrict__ Wt3,
    const u16* __restrict__ entries_bf, const u16* __restrict__ Wkv_t,
    const float* __restrict__ bq, const float* __restrict__ blk, const float* __restrict__ blv,
    const float* __restrict__ bk, const float* __restrict__ bv,
    const float* __restrict__ qn_w, const float* __restrict__ kn_w,
    const float* __restrict__ rc, const float* __restrict__ rs,
    u16* __restrict__ q_out, u16* __restrict__ lk_out, u16* __restrict__ lv_t,
    u16* __restrict__ ck_bf, u16* __restrict__ cv_t) {
  __shared__ __align__(16) u16 lds[32768];     // 64 KB: 2 x 32 KB (A 16K + B 16K)
  __shared__ float ps[2][2][64];               // 1 KB epilogue sumsq
  int tid = threadIdx.x, lane = tid & 63;
  int wave = tid >> 6;
  int wr = wave >> 1, wc = wave & 1;           // 2 x 2 waves
  int lin = blockIdx.x;
  int row0, col0, mode;
  const u16 *Ag, *Bg;
  if (lin < 768) {
    int swz = (lin & 7) * 96 + (lin >> 3);     // XCD-bijective 768 = 8*96
    row0 = (swz & 15) * 128; col0 = ((swz >> 4) & 15) * 128; mode = swz >> 8;
    Ag = A; Bg = Wt3 + (size_t)mode * HIDN * HIDN;
  } else {
    mode = 3; row0 = 0; col0 = (lin - 768) * 128;
    Ag = entries_bf; Bg = Wkv_t;
  }
  int rA = lane & 15, kg = lane >> 4;          // kg in [0,4)
  int srow = tid >> 3, sslot = tid & 7;        // srow in [0,32)
  int ssl = sslot ^ (srow & 7);                // inverse swizzle on SOURCE slot

  f32x4 acc[4][4];
  #pragma unroll
  for (int m = 0; m < 4; ++m)
    #pragma unroll
    for (int n = 0; n < 4; ++n) acc[m][n] = (f32x4){0.f, 0.f, 0.f, 0.f};

  // i 0-3: A 32-row slabs; i 4-7: B 32-row slabs
  auto stage = [&](int b, int i, int kt) {
    const u16* src = (i < 4) ? Ag : Bg;
    int rg = ((i < 4) ? row0 : col0) + ((i & 3) * 32) + srow;
    gl_lds16(&src[(size_t)rg * HIDN + kt * 64 + ssl * 8],
             &lds[b * 16384 + i * 2048 + tid * 8]);
  };
  auto rdA = [&](int b, int m, int ks) -> short8 {
    int r = wr * 64 + m * 16 + rA;
    int slot = (ks * 4 + kg) ^ (r & 7);
    return *(const short8*)&lds[b * 16384 + r * 64 + slot * 8];
  };
  auto rdB = [&](int b, int n, int ks) -> short8 {
    int r = wc * 64 + n * 16 + rA;
    int slot = (ks * 4 + kg) ^ (r & 7);
    return *(const short8*)&lds[b * 16384 + 8192 + r * 64 + slot * 8];
  };

  // prologue: tile 0 -> buf 0
  #pragma unroll
  for (int i = 0; i < 8; ++i) stage(0, i, 0);

  short8 Af[4], Bf[4][2];
  for (int u = 0; u < NKT; ++u) {
    int cur = u & 1;
    asm volatile("s_waitcnt vmcnt(0)" ::: "memory");
    __builtin_amdgcn_sched_barrier(0);
    __builtin_amdgcn_s_barrier();
    if (u + 1 < NKT) {
      #pragma unroll
      for (int i = 0; i < 8; ++i) stage(cur ^ 1, i, u + 1);
    }
    #pragma unroll
    for (int n = 0; n < 4; ++n) { Bf[n][0] = rdB(cur, n, 0); Bf[n][1] = rdB(cur, n, 1); }
    // sub-phase 1: ks0
    #pragma unroll
    for (int m = 0; m < 4; ++m) Af[m] = rdA(cur, m, 0);
    asm volatile("s_waitcnt lgkmcnt(0)" ::: "memory");
    __builtin_amdgcn_sched_barrier(0);
    __builtin_amdgcn_s_setprio(1);
    #pragma unroll
    for (int m = 0; m < 4; ++m)
      #pragma unroll
      for (int n = 0; n < 4; ++n)
        acc[m][n] = __builtin_amdgcn_mfma_f32_16x16x32_bf16(Af[m], Bf[n][0], acc[m][n], 0, 0, 0);
    __builtin_amdgcn_s_setprio(0);
    // sub-phase 2: ks1
    #pragma unroll
    for (int m = 0; m < 4; ++m) Af[m] = rdA(cur, m, 1);
    asm volatile("s_waitcnt lgkmcnt(0)" ::: "memory");
    __builtin_amdgcn_sched_barrier(0);
    __builtin_amdgcn_s_setprio(1);
    #pragma unroll
    for (int m = 0; m < 4; ++m)
      #pragma unroll
      for (int n = 0; n < 4; ++n)
        acc[m][n] = __builtin_amdgcn_mfma_f32_16x16x32_bf16(Af[m], Bf[n][1], acc[m][n], 0, 0, 0);
    __builtin_amdgcn_s_setprio(0);
  }

  // ---------------- epilogue (R5-verified 128-col forms)
  int rbase = kg * 4, cl = rA;
  int hh = col0 >> 7;
  #pragma unroll
  for (int n = 0; n < 4; ++n) {
    int dl = wc * 64 + n * 16 + cl;
    float bb;
    if (mode == 3)      bb = (col0 ? bv : bk)[dl];
    else if (mode == 0) bb = bq[col0 + dl];
    else if (mode == 1) bb = blk[col0 + dl];
    else                bb = blv[col0 + dl];
    #pragma unroll
    for (int m = 0; m < 4; ++m)
      #pragma unroll
      for (int j = 0; j < 4; ++j) acc[m][n][j] += bb;
  }

  if (mode == 2) {
    #pragma unroll
    for (int m = 0; m < 4; ++m) {
      int sb = row0 + wr * 64 + m * 16 + rbase;
      #pragma unroll
      for (int n = 0; n < 4; ++n) {
        int dl = wc * 64 + n * 16 + cl;
        ushort4 o;
        o.x = f2bf(acc[m][n][0]);
        o.y = f2bf(acc[m][n][1]);
        o.z = f2bf(acc[m][n][2]);
        o.w = f2bf(acc[m][n][3]);
        *(ushort4*)&lv_t[((size_t)hh * HDIM + dl) * S_LEN + sb] = o;
      }
    }
    return;
  }
  if (mode == 3 && col0 == 128) {
    // cv: transposed write cv_t[d][c]
    #pragma unroll
    for (int m = 0; m < 4; ++m) {
      int cchunk = wr * 64 + m * 16 + rbase;
      #pragma unroll
      for (int n = 0; n < 4; ++n) {
        int d = wc * 64 + n * 16 + cl;
        #pragma unroll
        for (int j = 0; j < 4; ++j)
          cv_t[(size_t)d * NCHNK + cchunk + j] = f2bf(acc[m][n][j]);
      }
    }
    return;
  }
  // rmsnorm + rope: modes 0 (q), 1 (lk), 3-ck
  {
    const float* nw = (mode == 0) ? qn_w : kn_w;
    #pragma unroll
    for (int m = 0; m < 4; ++m)
      #pragma unroll
      for (int j = 0; j < 4; ++j) {
        float s = acc[m][0][j] * acc[m][0][j] + acc[m][1][j] * acc[m][1][j]
                + acc[m][2][j] * acc[m][2][j] + acc[m][3][j] * acc[m][3][j];
        s += __shfl_xor(s, 1); s += __shfl_xor(s, 2);
        s += __shfl_xor(s, 4); s += __shfl_xor(s, 8);
        if (cl == 0) ps[wr][wc][m * 16 + rbase + j] = s;
      }
    __syncthreads();
    float nwv[4];
    #pragma unroll
    for (int n = 0; n < 4; ++n) nwv[n] = nw[wc * 64 + n * 16 + cl];
    #pragma unroll
    for (int m = 0; m < 4; ++m)
      #pragma unroll
      for (int j = 0; j < 4; ++j) {
        int r16 = m * 16 + rbase + j;
        int s = row0 + wr * 64 + r16;
        int pos = (mode == 3) ? (s * 16 + 15) : s;
        float rr2 = rsqrtf((ps[wr][0][r16] + ps[wr][1][r16]) * (1.f / 128.f) + 1e-6f);
        float o[4];
        if (wc == 0) {   // cols 0..63: rope pairs (n, n+2)
          #pragma unroll
          for (int n = 0; n < 2; ++n) {
            int i = n * 16 + cl;
            float ca = rc[pos * 32 + i], sa = rs[pos * 32 + i];
            float y1 = acc[m][n][j] * rr2 * nwv[n];
            float y2 = acc[m][n + 2][j] * rr2 * nwv[n + 2];
            o[n] = y1 * ca - y2 * sa;
            o[n + 2] = y1 * sa + y2 * ca;
          }
        } else {         // cols 64..127: pass-through
          #pragma unroll
          for (int n = 0; n < 4; ++n) o[n] = acc[m][n][j] * rr2 * nwv[n];
        }
        u16* dst;
        if (mode == 3) dst = ck_bf + (size_t)s * HDIM + wc * 64;
        else {
          u16* dstb = (mode == 0) ? q_out : lk_out;
          dst = dstb + ((size_t)hh * S_LEN + s) * HDIM + wc * 64;
        }
        #pragma unroll
        for (int n = 0; n < 4; ++n) dst[n * 16 + cl] = f2bf(o[n]);
      }
  }
}

// ---------------- out GEMM: pipelined 128^2, counted 1-deep, XCD swizzle (R10/R11 verified)
__global__ __launch_bounds__(256, 2) void k_gemm_out(const u16* __restrict__ A, const u16* __restrict__ Bt,
                                                     const float* __restrict__ bias, float* __restrict__ C) {
  __shared__ __align__(16) u16 lds[32768];     // 64 KB: 2 x 32 KB
  int tid = threadIdx.x, lane = tid & 63;
  int wave = tid >> 6;
  int wr = wave >> 1, wc = wave & 1;
  int lin = blockIdx.x + (blockIdx.y << 4);
  int swz = (lin & 7) * 32 + (lin >> 3);       // bijective 256 = 8*32
  int row0 = (swz & 15) * 128, col0 = (swz >> 4) * 128;
  int rA = lane & 15, kg = lane >> 4;
  int srow = tid >> 3, sslot = tid & 7;        // srow in [0,32)
  int ssl = sslot ^ (srow & 7);

  f32x4 acc[4][4];
  #pragma unroll
  for (int m = 0; m < 4; ++m)
    #pragma unroll
    for (int n = 0; n < 4; ++n) acc[m][n] = (f32x4){0.f, 0.f, 0.f, 0.f};

  auto stage = [&](int b, int i, int kt) {
    const u16* src = (i < 4) ? Bt : A;
    int rg = ((i < 4) ? col0 : row0) + (i & 3) * 32 + srow;
    int dofs = (i < 4) ? (8192 + i * 2048) : ((i - 4) * 2048);
    gl_lds16(&src[(size_t)rg * HIDN + kt * 64 + ssl * 8],
             &lds[b * 16384 + dofs + tid * 8]);
  };
  auto rdA = [&](int b, int m, int ks) -> short8 {
    int r = wr * 64 + m * 16 + rA;
    int slot = (ks * 4 + kg) ^ (r & 7);
    return *(const short8*)&lds[b * 16384 + r * 64 + slot * 8];
  };
  auto rdB = [&](int b, int n, int ks) -> short8 {
    int r = wc * 64 + n * 16 + rA;
    int slot = (ks * 4 + kg) ^ (r & 7);
    return *(const short8*)&lds[b * 16384 + 8192 + r * 64 + slot * 8];
  };

  #pragma unroll
  for (int i = 0; i < 8; ++i) stage(0, i, 0);

  short8 Af[4], Bf[4][2];
  for (int u = 0; u < NKT; ++u) {
    int cur = u & 1;
    bool pf = (u + 1 < NKT);
    if (pf) {
      #pragma unroll
      for (int i = 0; i < 8; ++i) stage(cur ^ 1, i, u + 1);
    }
    if (pf) asm volatile("s_waitcnt vmcnt(8)" ::: "memory");
    else    asm volatile("s_waitcnt vmcnt(0)" ::: "memory");
    __builtin_amdgcn_sched_barrier(0);
    __builtin_amdgcn_s_barrier();
    #pragma unroll
    for (int n = 0; n < 4; ++n) { Bf[n][0] = rdB(cur, n, 0); Bf[n][1] = rdB(cur, n, 1); }
    #pragma unroll
    for (int m = 0; m < 4; ++m) Af[m] = rdA(cur, m, 0);
    asm volatile("s_waitcnt lgkmcnt(0)" ::: "memory");
    __builtin_amdgcn_sched_barrier(0);
    __builtin_amdgcn_s_setprio(1);
    #pragma unroll
    for (int m = 0; m < 4; ++m)
      #pragma unroll
      for (int n = 0; n < 4; ++n)
        acc[m][n] = __builtin_amdgcn_mfma_f32_16x16x32_bf16(Af[m], Bf[n][0], acc[m][n], 0, 0, 0);
    __builtin_amdgcn_s_setprio(0);
    #pragma unroll
    for (int m = 0; m < 4; ++m) Af[m] = rdA(cur, m, 1);
    asm volatile("s_waitcnt lgkmcnt(0)" ::: "memory");
    __builtin_amdgcn_sched_barrier(0);
    __builtin_amdgcn_s_setprio(1);
    #pragma unroll
    for (int m = 0; m < 4; ++m)
      #pragma unroll
      for (int n = 0; n < 4; ++n)
        acc[m][n] = __builtin_amdgcn_mfma_f32_16x16x32_bf16(Af[m], Bf[n][1], acc[m][n], 0, 0, 0);
    __builtin_amdgcn_s_setprio(0);
    __builtin_amdgcn_s_barrier();
  }

  int rbase = kg * 4, cl = rA;
  #pragma unroll
  for (int m = 0; m < 4; ++m) {
    int rowb = row0 + wr * 64 + m * 16 + rbase;
    #pragma unroll
    for (int n = 0; n < 4; ++n) {
      int col = col0 + wc * 64 + n * 16 + cl;
      float bb = bias[col];
      #pragma unroll
      for (int j = 0; j < 4; ++j)
        C[(size_t)(rowb + j) * HIDN + col] = acc[m][n][j] + bb;
    }
  }
}

// ---------------- merged attention: compressed (+sink) then local, merged write
__global__ __launch_bounds__(256) void k_attn(const u16* __restrict__ q_bf, const u16* __restrict__ ck_bf,
                                              const u16* __restrict__ cv_t, const float* __restrict__ sink_k,
                                              const float* __restrict__ sink_v,
                                              const u16* __restrict__ lk_bf, const u16* __restrict__ lv_t,
                                              u16* __restrict__ merged) {
  __shared__ __align__(16) u16 kv[21760];
  __shared__ __align__(16) float sc[32][164];
  __shared__ __align__(16) u16 pb[32][168];
  int tid = threadIdx.x, lane = tid & 63, wave = tid >> 6;
  int lin = blockIdx.x;
  int sw = (lin & 7) * 128 + (lin >> 3);
  int s0 = (sw & 63) * 32, h = sw >> 6;
  const size_t hb = (size_t)h * S_LEN * HDIM;
  int rA = lane & 15, kg8 = (lane >> 4) * 8;
  int qt = wave & 1, wg = wave >> 1;

  short8 aq[4];
  #pragma unroll
  for (int c = 0; c < 4; ++c)
    aq[c] = *(const short8*)&q_bf[hb + (size_t)(s0 + qt * 16 + rA) * HDIM + c * 32 + kg8];

  // ======== compressed phase ========
  int cmax = s0 / 16 + 2; if (cmax > 128) cmax = 128;
  int nkeys = cmax + 1;
  int nkt = (nkeys + 15) >> 4, nkc = (nkeys + 31) >> 5;

  for (int i = tid; i < cmax * 16; i += 256) {
    int r = i >> 4, cz = (i & 15) * 8;
    *(uint4*)&kv[r * 136 + cz] = *(const uint4*)&ck_bf[r * HDIM + cz];
  }
  if (tid < 128) kv[cmax * 136 + tid] = f2bf(sink_k[h * HDIM + tid]);
  __syncthreads();

  for (int kt = wg; kt < nkt; kt += 2) {
    f32x4 a = (f32x4){0.f, 0.f, 0.f, 0.f};
    #pragma unroll
    for (int c = 0; c < 4; ++c) {
      short8 bk2 = *(const short8*)&kv[(kt * 16 + rA) * 136 + c * 32 + kg8];
      a = __builtin_amdgcn_mfma_f32_16x16x32_bf16(aq[c], bk2, a, 0, 0, 0);
    }
    int rq = qt * 16 + (lane >> 4) * 4;
    #pragma unroll
    for (int j = 0; j < 4; ++j) sc[rq + j][kt * 16 + rA] = a[j];
  }
  __syncthreads();

  { // softmax (8 lanes / row)
    int ql = tid >> 3, e = tid & 7, s = s0 + ql;
    int NK = nkc * 32;
    float m = -1e30f;
    for (int i = e; i < NK; i += 8) {
      if (i < nkeys) {
        float raw = sc[ql][i];
        bool valid = (i < cmax) ? (i * 16 + 15 <= s) : true;
        float v = valid ? raw * SCALE : -1e9f;
        sc[ql][i] = v;
        m = fmaxf(m, v);
      }
    }
    m = fmaxf(m, __shfl_xor(m, 1));
    m = fmaxf(m, __shfl_xor(m, 2));
    m = fmaxf(m, __shfl_xor(m, 4));
    float sum = 0.f;
    for (int i = e; i < NK; i += 8) {
      if (i < nkeys) {
        float pv = __expf(sc[ql][i] - m);
        sc[ql][i] = pv;
        sum += pv;
      }
    }
    sum += __shfl_xor(sum, 1);
    sum += __shfl_xor(sum, 2);
    sum += __shfl_xor(sum, 4);
    float inv = 1.f / sum;
    for (int i = e; i < NK; i += 8)
      pb[ql][i] = (i < nkeys) ? f2bf(sc[ql][i] * inv) : (u16)0;
  }
  __syncthreads();

  { // stage V^T (d x keys): uint4 bulk below cmax, scalar tail (sink + zeros)
    int d = tid & 127, half = tid >> 7;
    int ng = cmax >> 3;
    const u16* srcrow = cv_t + (size_t)d * NCHNK;
    for (int g = half; g < ng; g += 2)
      *(uint4*)&kv[d * 168 + g * 8] = *(const uint4*)&srcrow[g * 8];
    u16 sv = f2bf(sink_v[h * HDIM + d]);
    int NC = nkc * 32;
    for (int c = ng * 8 + half; c < NC; c += 2) {
      u16 v = (c < cmax) ? srcrow[c] : ((c == cmax) ? sv : (u16)0);
      kv[d * 168 + c] = v;
    }
  }
  __syncthreads();

  f32x4 po_c[4];
  #pragma unroll
  for (int n = 0; n < 4; ++n) po_c[n] = (f32x4){0.f, 0.f, 0.f, 0.f};
  for (int kc = 0; kc < nkc; ++kc) {
    short8 pfrag = *(const short8*)&pb[qt * 16 + rA][kc * 32 + kg8];
    #pragma unroll
    for (int n = 0; n < 4; ++n) {
      short8 av = *(const short8*)&kv[(wg * 64 + n * 16 + rA) * 168 + kc * 32 + kg8];
      po_c[n] = __builtin_amdgcn_mfma_f32_16x16x32_bf16(av, pfrag, po_c[n], 0, 0, 0);
    }
  }
  __syncthreads();

  // ======== local phase ========
  int tbase = s0 - 128;
  for (int i = tid; i < 160 * 16; i += 256) {
    int r = i >> 4, cz = (i & 15) * 8;
    int t = tbase + r;
    uint4 val = make_uint4(0, 0, 0, 0);
    if (t >= 0) val = *(const uint4*)&lk_bf[hb + (size_t)t * HDIM + cz];
    *(uint4*)&kv[r * 136 + cz] = val;
  }
  __syncthreads();

  for (int kt = wg; kt < 10; kt += 2) {
    f32x4 a = (f32x4){0.f, 0.f, 0.f, 0.f};
    #pragma unroll
    for (int c = 0; c < 4; ++c) {
      short8 bk2 = *(const short8*)&kv[(kt * 16 + rA) * 136 + c * 32 + kg8];
      a = __builtin_amdgcn_mfma_f32_16x16x32_bf16(aq[c], bk2, a, 0, 0, 0);
    }
    int rq = qt * 16 + (lane >> 4) * 4;
    #pragma unroll
    for (int j = 0; j < 4; ++j) sc[rq + j][kt * 16 + rA] = a[j];
  }
  __syncthreads();

  {
    int ql = tid >> 3, e = tid & 7;
    int ilo = 128 - s0; if (ql > ilo) ilo = ql;
    int ihi = ql + 128;
    float m = -1e30f;
    for (int i = e; i < 160; i += 8) {
      bool valid = (i >= ilo) && (i <= ihi);
      float v = valid ? sc[ql][i] * SCALE : -1e9f;
      sc[ql][i] = v;
      m = fmaxf(m, v);
    }
    m = fmaxf(m, __shfl_xor(m, 1));
    m = fmaxf(m, __shfl_xor(m, 2));
    m = fmaxf(m, __shfl_xor(m, 4));
    float sum = 0.f;
    for (int i = e; i < 160; i += 8) {
      float pv = __expf(sc[ql][i] - m);
      sc[ql][i] = pv;
      sum += pv;
    }
    sum += __shfl_xor(sum, 1);
    sum += __shfl_xor(sum, 2);
    sum += __shfl_xor(sum, 4);
    float inv = 1.f / sum;
    for (int i = e; i < 160; i += 8) pb[ql][i] = f2bf(sc[ql][i] * inv);
  }
  __syncthreads();

  {
    int d = tid & 127, c8s = tid >> 7;
    const size_t hbt = (size_t)h * HDIM * S_LEN;
    for (int c8 = c8s; c8 < 20; c8 += 2) {
      int t0 = tbase + c8 * 8;
      uint4 val = make_uint4(0, 0, 0, 0);
      if (t0 >= 0) val = *(const uint4*)&lv_t[hbt + (size_t)d * S_LEN + t0];
      *(uint4*)&kv[d * 168 + c8 * 8] = val;
    }
  }
  __syncthreads();

  {
    f32x4 po[4];
    #pragma unroll
    for (int n = 0; n < 4; ++n) po[n] = (f32x4){0.f, 0.f, 0.f, 0.f};
    #pragma unroll
    for (int kc = 0; kc < 5; ++kc) {
      short8 pfrag = *(const short8*)&pb[qt * 16 + rA][kc * 32 + kg8];
      #pragma unroll
      for (int n = 0; n < 4; ++n) {
        short8 av = *(const short8*)&kv[(wg * 64 + n * 16 + rA) * 168 + kc * 32 + kg8];
        po[n] = __builtin_amdgcn_mfma_f32_16x16x32_bf16(av, pfrag, po[n], 0, 0, 0);
      }
    }
    int q = qt * 16 + rA;
    int s = s0 + q;
    int rb = (lane >> 4) * 4;
    #pragma unroll
    for (int n = 0; n < 4; ++n) {
      int d0 = wg * 64 + n * 16 + rb;
      ushort4 o;
      o.x = f2bf(0.5f * (po[n][0] + po_c[n][0]));
      o.y = f2bf(0.5f * (po[n][1] + po_c[n][1]));
      o.z = f2bf(0.5f * (po[n][2] + po_c[n][2]));
      o.w = f2bf(0.5f * (po[n][3] + po_c[n][3]));
      *(ushort4*)&merged[(size_t)s * HIDN + h * HDIM + d0] = o;
    }
  }
}

extern "C" void kernel_launch(void* const* d_in, const int* in_sizes, int n_in,
                              void* d_out, int out_size, void* d_ws, size_t ws_size,
                              hipStream_t stream) {
  const float* hs     = (const float*)d_in[0];
  const float* Wq     = (const float*)d_in[1];
  const float* bq     = (const float*)d_in[2];
  const float* Wc     = (const float*)d_in[3];
  const float* bc     = (const float*)d_in[4];
  const float* Wk     = (const float*)d_in[5];
  const float* bk     = (const float*)d_in[6];
  const float* Wv     = (const float*)d_in[7];
  const float* bv     = (const float*)d_in[8];
  const float* Wlk    = (const float*)d_in[9];
  const float* blk    = (const float*)d_in[10];
  const float* Wlv    = (const float*)d_in[11];
  const float* blv    = (const float*)d_in[12];
  const float* qn_w   = (const float*)d_in[13];
  const float* kn_w   = (const float*)d_in[14];
  const float* sink_k = (const float*)d_in[15];
  const float* sink_v = (const float*)d_in[16];
  const float* Wo     = (const float*)d_in[17];
  const float* bo     = (const float*)d_in[18];
  float* out = (float*)d_out;

  char* p = (char*)d_ws;
  auto alloc = [&](size_t bytes) {
    char* r = p;
    p += (bytes + 255) & ~(size_t)255;
    return r;
  };
  float* rope_c  = (float*)alloc((size_t)S_LEN * 32 * 4);
  float* rope_s  = (float*)alloc((size_t)S_LEN * 32 * 4);
  u16*   hs_bf   = (u16*)  alloc((size_t)S_LEN * HIDN * 2);
  u16*   Wt3     = (u16*)  alloc((size_t)3 * HIDN * HIDN * 2);
  u16*   Wt_o    = (u16*)  alloc((size_t)HIDN * HIDN * 2);
  u16*   Wkv_t   = (u16*)  alloc((size_t)2 * HDIM * HIDN * 2);
  u16*   ent_bf  = (u16*)  alloc((size_t)256 * HIDN * 2);
  u16*   q_bf    = (u16*)  alloc((size_t)NHEAD * S_LEN * HDIM * 2);
  u16*   lk_bf   = (u16*)  alloc((size_t)NHEAD * S_LEN * HDIM * 2);
  u16*   lv_t    = (u16*)  alloc((size_t)NHEAD * HDIM * S_LEN * 2);
  u16*   ck_bf   = (u16*)  alloc((size_t)NCHNK * HDIM * 2);
  u16*   cv_t    = (u16*)  alloc((size_t)HDIM * NCHNK * 2);
  u16*   merged  = (u16*)  alloc((size_t)S_LEN * HIDN * 2);
  (void)ws_size; (void)in_sizes; (void)n_in; (void)out_size;

  // all preprocessing in one dispatch
  k_pre<<<dim3(64, 64, 6), dim3(32, 8), 0, stream>>>(Wq, Wlk, Wlv, Wo, hs, Wc, bc, Wk, Wv,
                                                     Wt3, Wt_o, hs_bf, rope_c, rope_s,
                                                     ent_bf, Wkv_t);

  // fused q/lk/lv + ck/cv projections (pipelined 128^2, 2 blocks/CU)
  k_gemm_qkv128<<<770, 256, 0, stream>>>(hs_bf, Wt3, ent_bf, Wkv_t,
                                         bq, blk, blv, bk, bv, qn_w, kn_w,
                                         rope_c, rope_s, q_bf, lk_bf, lv_t, ck_bf, cv_t);

  // merged attention (compressed + local + merge), XCD-chunked
  k_attn<<<1024, 256, 0, stream>>>(q_bf, ck_bf, cv_t, sink_k, sink_v,
                                   lk_bf, lv_t, merged);

  // output projection (pipelined 128^2)
  k_gemm_out<<<dim3(16, 16), 256, 0, stream>>>(merged, Wt_o, bo, out);
}

// Round 13
// 195.843 us; speedup vs baseline: 1.0234x; 1.0234x over previous
//
#include <hip/hip_runtime.h>

// HeavilyCompressedAttention on MI355X (gfx950). R13:
//  - exact R11 config (gemm256 = R9 1-barrier 256^2; pipelined gemm_out; k_pre)
//  - k_attn: T14 async-STAGE split — V loads issued to REGISTERS before the
//    QK^T/softmax phases (compressed: 8 predicated uint4; local: 10 uint4),
//    LDS writes deferred to the old stage position. Static indexing only.

typedef unsigned short u16;
typedef __attribute__((ext_vector_type(8))) short short8;
typedef __attribute__((ext_vector_type(4))) float f32x4;

#define S_LEN 2048
#define HIDN  2048
#define NHEAD 16
#define HDIM  128
#define NCHNK 128
#define NKT   32                      // K tiles of 64
#define SCALE 0.08838834764831845f   // 1/sqrt(128)

__device__ __forceinline__ float bf2f(u16 h) {
  return __uint_as_float(((unsigned)h) << 16);
}
__device__ __forceinline__ u16 f2bf(float f) {
  unsigned u = __float_as_uint(f);
  unsigned r = (u + 0x7fffu + ((u >> 16) & 1u)) >> 16;
  return (u16)r;
}

typedef __attribute__((address_space(3))) unsigned int lds_uint;
typedef __attribute__((address_space(1))) unsigned int glb_uint;
__device__ __forceinline__ void gl_lds16(const void* g, void* l) {
  __builtin_amdgcn_global_load_lds((glb_uint*)(unsigned long long)g,
                                   (lds_uint*)(unsigned)(unsigned long long)l,
                                   16, 0, 0);
}

// ---------------- fused preprocessing: grid (64,64,6), block (32,8)
__global__ __launch_bounds__(256) void k_pre(
    const float* __restrict__ Wq, const float* __restrict__ Wlk, const float* __restrict__ Wlv,
    const float* __restrict__ Wo, const float* __restrict__ hs,
    const float* __restrict__ Wc, const float* __restrict__ bc,
    const float* __restrict__ Wk, const float* __restrict__ Wv,
    u16* __restrict__ Wt3, u16* __restrict__ Wt_o, u16* __restrict__ hs_bf,
    float* __restrict__ rope_c, float* __restrict__ rope_s,
    u16* __restrict__ entries_bf, u16* __restrict__ Wkv_t) {
  __shared__ float tile[32][33];
  int z = blockIdx.z;
  int tx = threadIdx.x, ty = threadIdx.y;
  int tid = ty * 32 + tx;
  if (z < 4) {
    const float* src = (z == 0) ? Wq : (z == 1) ? Wlk : (z == 2) ? Wlv : Wo;
    u16* dst = (z < 3) ? (Wt3 + (size_t)z * HIDN * HIDN) : Wt_o;
    int k0 = blockIdx.x * 32, n0 = blockIdx.y * 32;
    #pragma unroll
    for (int i = 0; i < 32; i += 8)
      tile[ty + i][tx] = src[(size_t)(k0 + ty + i) * HIDN + (n0 + tx)];
    __syncthreads();
    #pragma unroll
    for (int i = 0; i < 32; i += 8)
      dst[(size_t)(n0 + ty + i) * HIDN + (k0 + tx)] = f2bf(tile[tx][ty + i]);
    return;
  }
  int bid = blockIdx.y * 64 + blockIdx.x;
  if (z == 4) {   // cast_hs
    size_t i4 = ((size_t)bid * 256 + tid) * 4;
    float4 v = *(const float4*)&hs[i4];
    ushort4 o;
    o.x = f2bf(v.x); o.y = f2bf(v.y); o.z = f2bf(v.z); o.w = f2bf(v.w);
    *(ushort4*)&hs_bf[i4] = o;
    return;
  }
  // z == 5
  if (bid < 256) {   // rope table
    int i = bid * 256 + tid;
    int pos = i >> 5, f = i & 31;
    float inv = __expf(-(float)f * (9.210340371976184f / 32.0f));
    float ang = (float)pos * inv;
    rope_c[i] = cosf(ang);
    rope_s[i] = sinf(ang);
    return;
  }
  if (bid < 384) {   // chunk_we, chunk c = bid-256
    __shared__ float red[16][17];
    __shared__ float wgt[16];
    int c = bid - 256;
    int row = tid >> 4, seg = tid & 15;
    const float* hrow = hs + ((size_t)c * 16 + row) * HIDN;
    float p = 0.f;
    #pragma unroll 8
    for (int k = seg * 128; k < seg * 128 + 128; k += 4) {
      float4 hv = *(const float4*)&hrow[k];
      float4 wv = *(const float4*)&Wc[k];
      p += hv.x * wv.x + hv.y * wv.y + hv.z * wv.z + hv.w * wv.w;
    }
    red[row][seg] = p;
    __syncthreads();
    if (tid < 16) {
      float lg = 0.f;
      #pragma unroll
      for (int j = 0; j < 16; ++j) lg += red[tid][j];
      lg += bc[0];
      float m = lg;
      #pragma unroll
      for (int msk = 1; msk <= 8; msk <<= 1) m = fmaxf(m, __shfl_xor(m, msk));
      float ev = __expf(lg - m);
      float sum = ev;
      #pragma unroll
      for (int msk = 1; msk <= 8; msk <<= 1) sum += __shfl_xor(sum, msk);
      wgt[tid] = ev / sum;
    }
    __syncthreads();
    #pragma unroll
    for (int j = 0; j < 8; ++j) {
      int hb = tid + j * 256;
      float acc = 0.f;
      #pragma unroll
      for (int r = 0; r < 16; ++r)
        acc += wgt[r] * hs[((size_t)c * 16 + r) * HIDN + hb];
      entries_bf[(size_t)c * HIDN + hb] = f2bf(acc);
    }
    return;
  }
  if (bid < 896) {   // transpose_w
    int idx = bid - 384;
    int zw = idx >> 8, byw = (idx >> 6) & 3, bxw = idx & 63;
    const float* src = zw ? Wv : Wk;
    u16* dst = Wkv_t + (size_t)zw * HDIM * 2048;
    int k0 = bxw * 32, n0 = byw * 32;
    #pragma unroll
    for (int i = 0; i < 32; i += 8)
      tile[ty + i][tx] = src[(size_t)(k0 + ty + i) * HDIM + (n0 + tx)];
    __syncthreads();
    #pragma unroll
    for (int i = 0; i < 32; i += 8)
      dst[(size_t)(n0 + ty + i) * 2048 + (k0 + tx)] = f2bf(tile[tx][ty + i]);
  }
}

// ---------------- 256x256 GEMM for q/lk/lv (+ck/cv block 192), R9 1-barrier pipeline
__global__ __launch_bounds__(512, 2) void k_gemm256(
    const u16* __restrict__ A, const u16* __restrict__ Wt3,
    const u16* __restrict__ entries_bf, const u16* __restrict__ Wkv_t,
    const float* __restrict__ bq, const float* __restrict__ blk, const float* __restrict__ blv,
    const float* __restrict__ bk, const float* __restrict__ bv,
    const float* __restrict__ qn_w, const float* __restrict__ kn_w,
    const float* __restrict__ rc, const float* __restrict__ rs,
    u16* __restrict__ q_out, u16* __restrict__ lk_out, u16* __restrict__ lv_t,
    u16* __restrict__ ck_bf, u16* __restrict__ cv_t) {
  __shared__ __align__(16) u16 lds[65536];     // 128 KB: 2 x 64 KB
  __shared__ float psq[2][4][128];             // 4 KB
  int tid = threadIdx.x, lane = tid & 63;
  int wid = tid >> 6;
  int wr = wid >> 2, wc = wid & 3;             // 2 x 4 waves
  int lin = blockIdx.x;
  int row0, col0, mode;
  const u16 *Ag, *Bg;
  if (lin < 192) {
    int swz = (lin & 7) * 24 + (lin >> 3);     // XCD-bijective 192 = 8*24
    mode = swz >> 6;
    int tile = swz & 63;
    row0 = (tile & 7) * 256;
    col0 = (tile >> 3) * 256;
    Ag = A; Bg = Wt3 + (size_t)mode * HIDN * HIDN;
  } else {
    mode = 3; row0 = 0; col0 = 0;
    Ag = entries_bf; Bg = Wkv_t;
  }
  int rA = lane & 15, kg = lane >> 4;          // kg in [0,4)
  int srow = tid >> 3, sslot = tid & 7;
  int ssl = sslot ^ (srow & 7);                // inverse swizzle on SOURCE slot

  f32x4 acc[8][4];
  #pragma unroll
  for (int m = 0; m < 8; ++m)
    #pragma unroll
    for (int n = 0; n < 4; ++n) acc[m][n] = (f32x4){0.f, 0.f, 0.f, 0.f};

  auto stage = [&](int b, int i, int kt) {
    const u16* src = (i < 4) ? Ag : Bg;
    int rg = ((i < 4) ? row0 : col0) + ((i & 3) * 64) + srow;
    gl_lds16(&src[(size_t)rg * HIDN + kt * 64 + ssl * 8],
             &lds[b * 32768 + i * 4096 + tid * 8]);
  };
  auto rdA = [&](int b, int m, int ks) -> short8 {
    int r = wr * 128 + m * 16 + rA;
    int slot = (ks * 4 + kg) ^ (r & 7);
    return *(const short8*)&lds[b * 32768 + r * 64 + slot * 8];
  };
  auto rdB = [&](int b, int n, int ks) -> short8 {
    int r = wc * 64 + n * 16 + rA;
    int slot = (ks * 4 + kg) ^ (r & 7);
    return *(const short8*)&lds[b * 32768 + 16384 + r * 64 + slot * 8];
  };

  // prologue: tile 0 -> buf 0
  #pragma unroll
  for (int i = 0; i < 8; ++i) stage(0, i, 0);

  short8 Af[4], Bf[4][2];
  for (int u = 0; u < NKT; ++u) {
    int cur = u & 1;
    asm volatile("s_waitcnt vmcnt(0)" ::: "memory");
    __builtin_amdgcn_sched_barrier(0);
    __builtin_amdgcn_s_barrier();
    if (u + 1 < NKT) {
      #pragma unroll
      for (int i = 0; i < 8; ++i) stage(cur ^ 1, i, u + 1);
    }
    #pragma unroll
    for (int n = 0; n < 4; ++n) { Bf[n][0] = rdB(cur, n, 0); Bf[n][1] = rdB(cur, n, 1); }
    // sub-phase 1: A m0-3 ks0
    #pragma unroll
    for (int m = 0; m < 4; ++m) Af[m] = rdA(cur, m, 0);
    asm volatile("s_waitcnt lgkmcnt(0)" ::: "memory");
    __builtin_amdgcn_sched_barrier(0);
    __builtin_amdgcn_s_setprio(1);
    #pragma unroll
    for (int m = 0; m < 4; ++m)
      #pragma unroll
      for (int n = 0; n < 4; ++n)
        acc[m][n] = __builtin_amdgcn_mfma_f32_16x16x32_bf16(Af[m], Bf[n][0], acc[m][n], 0, 0, 0);
    __builtin_amdgcn_s_setprio(0);
    // sub-phase 2: A m0-3 ks1
    #pragma unroll
    for (int m = 0; m < 4; ++m) Af[m] = rdA(cur, m, 1);
    asm volatile("s_waitcnt lgkmcnt(0)" ::: "memory");
    __builtin_amdgcn_sched_barrier(0);
    __builtin_amdgcn_s_setprio(1);
    #pragma unroll
    for (int m = 0; m < 4; ++m)
      #pragma unroll
      for (int n = 0; n < 4; ++n)
        acc[m][n] = __builtin_amdgcn_mfma_f32_16x16x32_bf16(Af[m], Bf[n][1], acc[m][n], 0, 0, 0);
    __builtin_amdgcn_s_setprio(0);
    // sub-phase 3: A m4-7 ks0
    #pragma unroll
    for (int m = 0; m < 4; ++m) Af[m] = rdA(cur, m + 4, 0);
    asm volatile("s_waitcnt lgkmcnt(0)" ::: "memory");
    __builtin_amdgcn_sched_barrier(0);
    __builtin_amdgcn_s_setprio(1);
    #pragma unroll
    for (int m = 0; m < 4; ++m)
      #pragma unroll
      for (int n = 0; n < 4; ++n)
        acc[m + 4][n] = __builtin_amdgcn_mfma_f32_16x16x32_bf16(Af[m], Bf[n][0], acc[m + 4][n], 0, 0, 0);
    __builtin_amdgcn_s_setprio(0);
    // sub-phase 4: A m4-7 ks1
    #pragma unroll
    for (int m = 0; m < 4; ++m) Af[m] = rdA(cur, m + 4, 1);
    asm volatile("s_waitcnt lgkmcnt(0)" ::: "memory");
    __builtin_amdgcn_sched_barrier(0);
    __builtin_amdgcn_s_setprio(1);
    #pragma unroll
    for (int m = 0; m < 4; ++m)
      #pragma unroll
      for (int n = 0; n < 4; ++n)
        acc[m + 4][n] = __builtin_amdgcn_mfma_f32_16x16x32_bf16(Af[m], Bf[n][1], acc[m + 4][n], 0, 0, 0);
    __builtin_amdgcn_s_setprio(0);
  }

  // ---------------- epilogue
  int cl = rA, rbase = kg * 4;
  #pragma unroll
  for (int n = 0; n < 4; ++n) {
    int dl = wc * 64 + n * 16 + cl;
    float bb;
    if (mode == 3)      bb = (dl < 128) ? bk[dl] : bv[dl - 128];
    else if (mode == 0) bb = bq[col0 + dl];
    else if (mode == 1) bb = blk[col0 + dl];
    else                bb = blv[col0 + dl];
    #pragma unroll
    for (int m = 0; m < 8; ++m)
      #pragma unroll
      for (int j = 0; j < 4; ++j) acc[m][n][j] += bb;
  }

  if (mode == 2) {
    int hh = (col0 >> 7) + (wc >> 1);
    #pragma unroll
    for (int m = 0; m < 8; ++m) {
      int sb = row0 + wr * 128 + m * 16 + rbase;
      #pragma unroll
      for (int n = 0; n < 4; ++n) {
        int dl = (wc & 1) * 64 + n * 16 + cl;
        ushort4 o;
        o.x = f2bf(acc[m][n][0]);
        o.y = f2bf(acc[m][n][1]);
        o.z = f2bf(acc[m][n][2]);
        o.w = f2bf(acc[m][n][3]);
        *(ushort4*)&lv_t[((size_t)hh * HDIM + dl) * S_LEN + sb] = o;
      }
    }
    return;
  }

  bool is_cv = (mode == 3) && (wc >= 2);
  if (!is_cv) {
    #pragma unroll
    for (int m = 0; m < 8; ++m)
      #pragma unroll
      for (int j = 0; j < 4; ++j) {
        float s2 = acc[m][0][j] * acc[m][0][j] + acc[m][1][j] * acc[m][1][j]
                 + acc[m][2][j] * acc[m][2][j] + acc[m][3][j] * acc[m][3][j];
        s2 += __shfl_xor(s2, 1); s2 += __shfl_xor(s2, 2);
        s2 += __shfl_xor(s2, 4); s2 += __shfl_xor(s2, 8);
        if (cl == 0) psq[wr][wc][m * 16 + rbase + j] = s2;
      }
  }
  __syncthreads();
  if (is_cv) {
    if (wr == 0) {
      #pragma unroll
      for (int m = 0; m < 8; ++m) {
        int cchunk = m * 16 + rbase;
        #pragma unroll
        for (int n = 0; n < 4; ++n) {
          int d = (wc - 2) * 64 + n * 16 + cl;
          #pragma unroll
          for (int j = 0; j < 4; ++j)
            cv_t[(size_t)d * NCHNK + cchunk + j] = f2bf(acc[m][n][j]);
        }
      }
    }
    return;
  }
  {
    const float* nw = (mode == 0) ? qn_w : kn_w;
    int hgrp = wc >> 1;
    float nwv[4];
    #pragma unroll
    for (int n = 0; n < 4; ++n) nwv[n] = nw[(wc & 1) * 64 + n * 16 + cl];
    #pragma unroll
    for (int m = 0; m < 8; ++m)
      #pragma unroll
      for (int j = 0; j < 4; ++j) {
        int r16 = m * 16 + rbase + j;
        int s = row0 + wr * 128 + r16;
        bool valid = (mode != 3) || (s < NCHNK);
        int sc2 = valid ? s : 0;
        int pos = (mode == 3) ? (sc2 * 16 + 15) : sc2;
        float rr2 = rsqrtf((psq[wr][hgrp * 2][r16] + psq[wr][hgrp * 2 + 1][r16]) * (1.f / 128.f) + 1e-6f);
        float o[4];
        if ((wc & 1) == 0) {
          #pragma unroll
          for (int n = 0; n < 2; ++n) {
            int i = n * 16 + cl;
            float ca = rc[pos * 32 + i], sa = rs[pos * 32 + i];
            float y1 = acc[m][n][j] * rr2 * nwv[n];
            float y2 = acc[m][n + 2][j] * rr2 * nwv[n + 2];
            o[n] = y1 * ca - y2 * sa;
            o[n + 2] = y1 * sa + y2 * ca;
          }
        } else {
          #pragma unroll
          for (int n = 0; n < 4; ++n) o[n] = acc[m][n][j] * rr2 * nwv[n];
        }
        if (valid) {
          u16* dst;
          if (mode == 3) dst = ck_bf + (size_t)s * HDIM + (wc & 1) * 64;
          else {
            u16* dstb = (mode == 0) ? q_out : lk_out;
            dst = dstb + ((size_t)((col0 >> 7) + hgrp) * S_LEN + s) * HDIM + (wc & 1) * 64;
          }
          #pragma unroll
          for (int n = 0; n < 4; ++n) dst[n * 16 + cl] = f2bf(o[n]);
        }
      }
  }
}

// ---------------- out GEMM: pipelined 128^2, counted 1-deep, XCD swizzle
__global__ __launch_bounds__(256, 2) void k_gemm_out(const u16* __restrict__ A, const u16* __restrict__ Bt,
                                                     const float* __restrict__ bias, float* __restrict__ C) {
  __shared__ __align__(16) u16 lds[32768];     // 64 KB: 2 x 32 KB
  int tid = threadIdx.x, lane = tid & 63;
  int wave = tid >> 6;
  int wr = wave >> 1, wc = wave & 1;
  int lin = blockIdx.x + (blockIdx.y << 4);
  int swz = (lin & 7) * 32 + (lin >> 3);       // bijective 256 = 8*32
  int row0 = (swz & 15) * 128, col0 = (swz >> 4) * 128;
  int rA = lane & 15, kg = lane >> 4;
  int srow = tid >> 3, sslot = tid & 7;        // srow in [0,32)
  int ssl = sslot ^ (srow & 7);

  f32x4 acc[4][4];
  #pragma unroll
  for (int m = 0; m < 4; ++m)
    #pragma unroll
    for (int n = 0; n < 4; ++n) acc[m][n] = (f32x4){0.f, 0.f, 0.f, 0.f};

  auto stage = [&](int b, int i, int kt) {
    const u16* src = (i < 4) ? Bt : A;
    int rg = ((i < 4) ? col0 : row0) + (i & 3) * 32 + srow;
    int dofs = (i < 4) ? (8192 + i * 2048) : ((i - 4) * 2048);
    gl_lds16(&src[(size_t)rg * HIDN + kt * 64 + ssl * 8],
             &lds[b * 16384 + dofs + tid * 8]);
  };
  auto rdA = [&](int b, int m, int ks) -> short8 {
    int r = wr * 64 + m * 16 + rA;
    int slot = (ks * 4 + kg) ^ (r & 7);
    return *(const short8*)&lds[b * 16384 + r * 64 + slot * 8];
  };
  auto rdB = [&](int b, int n, int ks) -> short8 {
    int r = wc * 64 + n * 16 + rA;
    int slot = (ks * 4 + kg) ^ (r & 7);
    return *(const short8*)&lds[b * 16384 + 8192 + r * 64 + slot * 8];
  };

  #pragma unroll
  for (int i = 0; i < 8; ++i) stage(0, i, 0);

  short8 Af[4], Bf[4][2];
  for (int u = 0; u < NKT; ++u) {
    int cur = u & 1;
    bool pf = (u + 1 < NKT);
    if (pf) {
      #pragma unroll
      for (int i = 0; i < 8; ++i) stage(cur ^ 1, i, u + 1);
    }
    if (pf) asm volatile("s_waitcnt vmcnt(8)" ::: "memory");
    else    asm volatile("s_waitcnt vmcnt(0)" ::: "memory");
    __builtin_amdgcn_sched_barrier(0);
    __builtin_amdgcn_s_barrier();
    #pragma unroll
    for (int n = 0; n < 4; ++n) { Bf[n][0] = rdB(cur, n, 0); Bf[n][1] = rdB(cur, n, 1); }
    #pragma unroll
    for (int m = 0; m < 4; ++m) Af[m] = rdA(cur, m, 0);
    asm volatile("s_waitcnt lgkmcnt(0)" ::: "memory");
    __builtin_amdgcn_sched_barrier(0);
    __builtin_amdgcn_s_setprio(1);
    #pragma unroll
    for (int m = 0; m < 4; ++m)
      #pragma unroll
      for (int n = 0; n < 4; ++n)
        acc[m][n] = __builtin_amdgcn_mfma_f32_16x16x32_bf16(Af[m], Bf[n][0], acc[m][n], 0, 0, 0);
    __builtin_amdgcn_s_setprio(0);
    #pragma unroll
    for (int m = 0; m < 4; ++m) Af[m] = rdA(cur, m, 1);
    asm volatile("s_waitcnt lgkmcnt(0)" ::: "memory");
    __builtin_amdgcn_sched_barrier(0);
    __builtin_amdgcn_s_setprio(1);
    #pragma unroll
    for (int m = 0; m < 4; ++m)
      #pragma unroll
      for (int n = 0; n < 4; ++n)
        acc[m][n] = __builtin_amdgcn_mfma_f32_16x16x32_bf16(Af[m], Bf[n][1], acc[m][n], 0, 0, 0);
    __builtin_amdgcn_s_setprio(0);
    __builtin_amdgcn_s_barrier();
  }

  int rbase = kg * 4, cl = rA;
  #pragma unroll
  for (int m = 0; m < 4; ++m) {
    int rowb = row0 + wr * 64 + m * 16 + rbase;
    #pragma unroll
    for (int n = 0; n < 4; ++n) {
      int col = col0 + wc * 64 + n * 16 + cl;
      float bb = bias[col];
      #pragma unroll
      for (int j = 0; j < 4; ++j)
        C[(size_t)(rowb + j) * HIDN + col] = acc[m][n][j] + bb;
    }
  }
}

// ---------------- merged attention with T14 async V staging
__global__ __launch_bounds__(256) void k_attn(const u16* __restrict__ q_bf, const u16* __restrict__ ck_bf,
                                              const u16* __restrict__ cv_t, const float* __restrict__ sink_k,
                                              const float* __restrict__ sink_v,
                                              const u16* __restrict__ lk_bf, const u16* __restrict__ lv_t,
                                              u16* __restrict__ merged) {
  __shared__ __align__(16) u16 kv[21760];
  __shared__ __align__(16) float sc[32][164];
  __shared__ __align__(16) u16 pb[32][168];
  int tid = threadIdx.x, lane = tid & 63, wave = tid >> 6;
  int lin = blockIdx.x;
  int sw = (lin & 7) * 128 + (lin >> 3);
  int s0 = (sw & 63) * 32, h = sw >> 6;
  const size_t hb = (size_t)h * S_LEN * HDIM;
  int rA = lane & 15, kg8 = (lane >> 4) * 8;
  int qt = wave & 1, wg = wave >> 1;

  short8 aq[4];
  #pragma unroll
  for (int c = 0; c < 4; ++c)
    aq[c] = *(const short8*)&q_bf[hb + (size_t)(s0 + qt * 16 + rA) * HDIM + c * 32 + kg8];

  // ======== compressed phase ========
  int cmax = s0 / 16 + 2; if (cmax > 128) cmax = 128;
  int nkeys = cmax + 1;
  int nkt = (nkeys + 15) >> 4, nkc = (nkeys + 31) >> 5;

  // T14: issue cv_t loads into registers EARLY (predicated static unroll)
  int dV = tid & 127, halfV = tid >> 7;
  int ng = cmax >> 3;
  const u16* cvrow = cv_t + (size_t)dV * NCHNK;
  uint4 vv[8];
  #pragma unroll
  for (int i = 0; i < 8; ++i) {
    int g = halfV + 2 * i;
    vv[i] = make_uint4(0, 0, 0, 0);
    if (g < ng) vv[i] = *(const uint4*)&cvrow[g * 8];
  }
  float svf = sink_v[h * HDIM + dV];

  for (int i = tid; i < cmax * 16; i += 256) {
    int r = i >> 4, cz = (i & 15) * 8;
    *(uint4*)&kv[r * 136 + cz] = *(const uint4*)&ck_bf[r * HDIM + cz];
  }
  if (tid < 128) kv[cmax * 136 + tid] = f2bf(sink_k[h * HDIM + tid]);
  __syncthreads();

  for (int kt = wg; kt < nkt; kt += 2) {
    f32x4 a = (f32x4){0.f, 0.f, 0.f, 0.f};
    #pragma unroll
    for (int c = 0; c < 4; ++c) {
      short8 bk2 = *(const short8*)&kv[(kt * 16 + rA) * 136 + c * 32 + kg8];
      a = __builtin_amdgcn_mfma_f32_16x16x32_bf16(aq[c], bk2, a, 0, 0, 0);
    }
    int rq = qt * 16 + (lane >> 4) * 4;
    #pragma unroll
    for (int j = 0; j < 4; ++j) sc[rq + j][kt * 16 + rA] = a[j];
  }
  __syncthreads();

  { // softmax (8 lanes / row)
    int ql = tid >> 3, e = tid & 7, s = s0 + ql;
    int NK = nkc * 32;
    float m = -1e30f;
    for (int i = e; i < NK; i += 8) {
      if (i < nkeys) {
        float raw = sc[ql][i];
        bool valid = (i < cmax) ? (i * 16 + 15 <= s) : true;
        float v = valid ? raw * SCALE : -1e9f;
        sc[ql][i] = v;
        m = fmaxf(m, v);
      }
    }
    m = fmaxf(m, __shfl_xor(m, 1));
    m = fmaxf(m, __shfl_xor(m, 2));
    m = fmaxf(m, __shfl_xor(m, 4));
    float sum = 0.f;
    for (int i = e; i < NK; i += 8) {
      if (i < nkeys) {
        float pv = __expf(sc[ql][i] - m);
        sc[ql][i] = pv;
        sum += pv;
      }
    }
    sum += __shfl_xor(sum, 1);
    sum += __shfl_xor(sum, 2);
    sum += __shfl_xor(sum, 4);
    float inv = 1.f / sum;
    for (int i = e; i < NK; i += 8)
      pb[ql][i] = (i < nkeys) ? f2bf(sc[ql][i] * inv) : (u16)0;
  }
  __syncthreads();

  { // write V^T from pre-issued registers + scalar tail
    #pragma unroll
    for (int i = 0; i < 8; ++i) {
      int g = halfV + 2 * i;
      if (g < ng) *(uint4*)&kv[dV * 168 + g * 8] = vv[i];
    }
    u16 sv = f2bf(svf);
    int NC = nkc * 32;
    for (int c = ng * 8 + halfV; c < NC; c += 2) {
      u16 v = (c < cmax) ? cvrow[c] : ((c == cmax) ? sv : (u16)0);
      kv[dV * 168 + c] = v;
    }
  }
  __syncthreads();

  f32x4 po_c[4];
  #pragma unroll
  for (int n = 0; n < 4; ++n) po_c[n] = (f32x4){0.f, 0.f, 0.f, 0.f};
  for (int kc = 0; kc < nkc; ++kc) {
    short8 pfrag = *(const short8*)&pb[qt * 16 + rA][kc * 32 + kg8];
    #pragma unroll
    for (int n = 0; n < 4; ++n) {
      short8 av = *(const short8*)&kv[(wg * 64 + n * 16 + rA) * 168 + kc * 32 + kg8];
      po_c[n] = __builtin_amdgcn_mfma_f32_16x16x32_bf16(av, pfrag, po_c[n], 0, 0, 0);
    }
  }
  __syncthreads();

  // ======== local phase ========
  int tbase = s0 - 128;
  // T14: issue lv_t loads into registers while staging K
  uint4 lvv[10];
  {
    const size_t hbt = (size_t)h * HDIM * S_LEN;
    #pragma unroll
    for (int i = 0; i < 10; ++i) {
      int c8 = halfV + 2 * i;
      int t0 = tbase + c8 * 8;
      lvv[i] = make_uint4(0, 0, 0, 0);
      if (t0 >= 0) lvv[i] = *(const uint4*)&lv_t[hbt + (size_t)dV * S_LEN + t0];
    }
  }
  for (int i = tid; i < 160 * 16; i += 256) {
    int r = i >> 4, cz = (i & 15) * 8;
    int t = tbase + r;
    uint4 val = make_uint4(0, 0, 0, 0);
    if (t >= 0) val = *(const uint4*)&lk_bf[hb + (size_t)t * HDIM + cz];
    *(uint4*)&kv[r * 136 + cz] = val;
  }
  __syncthreads();

  for (int kt = wg; kt < 10; kt += 2) {
    f32x4 a = (f32x4){0.f, 0.f, 0.f, 0.f};
    #pragma unroll
    for (int c = 0; c < 4; ++c) {
      short8 bk2 = *(const short8*)&kv[(kt * 16 + rA) * 136 + c * 32 + kg8];
      a = __builtin_amdgcn_mfma_f32_16x16x32_bf16(aq[c], bk2, a, 0, 0, 0);
    }
    int rq = qt * 16 + (lane >> 4) * 4;
    #pragma unroll
    for (int j = 0; j < 4; ++j) sc[rq + j][kt * 16 + rA] = a[j];
  }
  __syncthreads();

  {
    int ql = tid >> 3, e = tid & 7;
    int ilo = 128 - s0; if (ql > ilo) ilo = ql;
    int ihi = ql + 128;
    float m = -1e30f;
    for (int i = e; i < 160; i += 8) {
      bool valid = (i >= ilo) && (i <= ihi);
      float v = valid ? sc[ql][i] * SCALE : -1e9f;
      sc[ql][i] = v;
      m = fmaxf(m, v);
    }
    m = fmaxf(m, __shfl_xor(m, 1));
    m = fmaxf(m, __shfl_xor(m, 2));
    m = fmaxf(m, __shfl_xor(m, 4));
    float sum = 0.f;
    for (int i = e; i < 160; i += 8) {
      float pv = __expf(sc[ql][i] - m);
      sc[ql][i] = pv;
      sum += pv;
    }
    sum += __shfl_xor(sum, 1);
    sum += __shfl_xor(sum, 2);
    sum += __shfl_xor(sum, 4);
    float inv = 1.f / sum;
    for (int i = e; i < 160; i += 8) pb[ql][i] = f2bf(sc[ql][i] * inv);
  }
  __syncthreads();

  { // write V^T from pre-issued registers
    #pragma unroll
    for (int i = 0; i < 10; ++i) {
      int c8 = halfV + 2 * i;
      *(uint4*)&kv[dV * 168 + c8 * 8] = lvv[i];
    }
  }
  __syncthreads();

  {
    f32x4 po[4];
    #pragma unroll
    for (int n = 0; n < 4; ++n) po[n] = (f32x4){0.f, 0.f, 0.f, 0.f};
    #pragma unroll
    for (int kc = 0; kc < 5; ++kc) {
      short8 pfrag = *(const short8*)&pb[qt * 16 + rA][kc * 32 + kg8];
      #pragma unroll
      for (int n = 0; n < 4; ++n) {
        short8 av = *(const short8*)&kv[(wg * 64 + n * 16 + rA) * 168 + kc * 32 + kg8];
        po[n] = __builtin_amdgcn_mfma_f32_16x16x32_bf16(av, pfrag, po[n], 0, 0, 0);
      }
    }
    int q = qt * 16 + rA;
    int s = s0 + q;
    int rb = (lane >> 4) * 4;
    #pragma unroll
    for (int n = 0; n < 4; ++n) {
      int d0 = wg * 64 + n * 16 + rb;
      ushort4 o;
      o.x = f2bf(0.5f * (po[n][0] + po_c[n][0]));
      o.y = f2bf(0.5f * (po[n][1] + po_c[n][1]));
      o.z = f2bf(0.5f * (po[n][2] + po_c[n][2]));
      o.w = f2bf(0.5f * (po[n][3] + po_c[n][3]));
      *(ushort4*)&merged[(size_t)s * HIDN + h * HDIM + d0] = o;
    }
  }
}

extern "C" void kernel_launch(void* const* d_in, const int* in_sizes, int n_in,
                              void* d_out, int out_size, void* d_ws, size_t ws_size,
                              hipStream_t stream) {
  const float* hs     = (const float*)d_in[0];
  const float* Wq     = (const float*)d_in[1];
  const float* bq     = (const float*)d_in[2];
  const float* Wc     = (const float*)d_in[3];
  const float* bc     = (const float*)d_in[4];
  const float* Wk     = (const float*)d_in[5];
  const float* bk     = (const float*)d_in[6];
  const float* Wv     = (const float*)d_in[7];
  const float* bv     = (const float*)d_in[8];
  const float* Wlk    = (const float*)d_in[9];
  const float* blk    = (const float*)d_in[10];
  const float* Wlv    = (const float*)d_in[11];
  const float* blv    = (const float*)d_in[12];
  const float* qn_w   = (const float*)d_in[13];
  const float* kn_w   = (const float*)d_in[14];
  const float* sink_k = (const float*)d_in[15];
  const float* sink_v = (const float*)d_in[16];
  const float* Wo     = (const float*)d_in[17];
  const float* bo     = (const float*)d_in[18];
  float* out = (float*)d_out;

  char* p = (char*)d_ws;
  auto alloc = [&](size_t bytes) {
    char* r = p;
    p += (bytes + 255) & ~(size_t)255;
    return r;
  };
  float* rope_c  = (float*)alloc((size_t)S_LEN * 32 * 4);
  float* rope_s  = (float*)alloc((size_t)S_LEN * 32 * 4);
  u16*   hs_bf   = (u16*)  alloc((size_t)S_LEN * HIDN * 2);
  u16*   Wt3     = (u16*)  alloc((size_t)3 * HIDN * HIDN * 2);
  u16*   Wt_o    = (u16*)  alloc((size_t)HIDN * HIDN * 2);
  u16*   Wkv_t   = (u16*)  alloc((size_t)2 * HDIM * HIDN * 2);
  u16*   ent_bf  = (u16*)  alloc((size_t)256 * HIDN * 2);
  u16*   q_bf    = (u16*)  alloc((size_t)NHEAD * S_LEN * HDIM * 2);
  u16*   lk_bf   = (u16*)  alloc((size_t)NHEAD * S_LEN * HDIM * 2);
  u16*   lv_t    = (u16*)  alloc((size_t)NHEAD * HDIM * S_LEN * 2);
  u16*   ck_bf   = (u16*)  alloc((size_t)NCHNK * HDIM * 2);
  u16*   cv_t    = (u16*)  alloc((size_t)HDIM * NCHNK * 2);
  u16*   merged  = (u16*)  alloc((size_t)S_LEN * HIDN * 2);
  (void)ws_size; (void)in_sizes; (void)n_in; (void)out_size;

  // all preprocessing in one dispatch
  k_pre<<<dim3(64, 64, 6), dim3(32, 8), 0, stream>>>(Wq, Wlk, Wlv, Wo, hs, Wc, bc, Wk, Wv,
                                                     Wt3, Wt_o, hs_bf, rope_c, rope_s,
                                                     ent_bf, Wkv_t);

  // fused q/lk/lv + ck/cv projections (R9 pipelined 256^2)
  k_gemm256<<<193, 512, 0, stream>>>(hs_bf, Wt3, ent_bf, Wkv_t,
                                     bq, blk, blv, bk, bv, qn_w, kn_w,
                                     rope_c, rope_s, q_bf, lk_bf, lv_t, ck_bf, cv_t);

  // merged attention (compressed + local + merge), XCD-chunked, async V staging
  k_attn<<<1024, 256, 0, stream>>>(q_bf, ck_bf, cv_t, sink_k, sink_v,
                                   lk_bf, lv_t, merged);

  // output projection (pipelined 128^2)
  k_gemm_out<<<dim3(16, 16), 256, 0, stream>>>(merged, Wt_o, bo, out);
}

// Round 14
// 195.517 us; speedup vs baseline: 1.0251x; 1.0017x over previous
//
#include <hip/hip_runtime.h>

// HeavilyCompressedAttention on MI355X (gfx950). R14:
//  - k_gemm256: quadrant-chunked XCD tile mapping (per-XCD L2 working set
//    9.5MB -> ~4-8MB; A-panel reads become L2 hits). K-loop/epilogues
//    byte-identical to R13.
//  - everything else identical to R13 (verified, 195.8us).

typedef unsigned short u16;
typedef __attribute__((ext_vector_type(8))) short short8;
typedef __attribute__((ext_vector_type(4))) float f32x4;

#define S_LEN 2048
#define HIDN  2048
#define NHEAD 16
#define HDIM  128
#define NCHNK 128
#define NKT   32                      // K tiles of 64
#define SCALE 0.08838834764831845f   // 1/sqrt(128)

__device__ __forceinline__ float bf2f(u16 h) {
  return __uint_as_float(((unsigned)h) << 16);
}
__device__ __forceinline__ u16 f2bf(float f) {
  unsigned u = __float_as_uint(f);
  unsigned r = (u + 0x7fffu + ((u >> 16) & 1u)) >> 16;
  return (u16)r;
}

typedef __attribute__((address_space(3))) unsigned int lds_uint;
typedef __attribute__((address_space(1))) unsigned int glb_uint;
__device__ __forceinline__ void gl_lds16(const void* g, void* l) {
  __builtin_amdgcn_global_load_lds((glb_uint*)(unsigned long long)g,
                                   (lds_uint*)(unsigned)(unsigned long long)l,
                                   16, 0, 0);
}

// ---------------- fused preprocessing: grid (64,64,6), block (32,8)
__global__ __launch_bounds__(256) void k_pre(
    const float* __restrict__ Wq, const float* __restrict__ Wlk, const float* __restrict__ Wlv,
    const float* __restrict__ Wo, const float* __restrict__ hs,
    const float* __restrict__ Wc, const float* __restrict__ bc,
    const float* __restrict__ Wk, const float* __restrict__ Wv,
    u16* __restrict__ Wt3, u16* __restrict__ Wt_o, u16* __restrict__ hs_bf,
    float* __restrict__ rope_c, float* __restrict__ rope_s,
    u16* __restrict__ entries_bf, u16* __restrict__ Wkv_t) {
  __shared__ float tile[32][33];
  int z = blockIdx.z;
  int tx = threadIdx.x, ty = threadIdx.y;
  int tid = ty * 32 + tx;
  if (z < 4) {
    const float* src = (z == 0) ? Wq : (z == 1) ? Wlk : (z == 2) ? Wlv : Wo;
    u16* dst = (z < 3) ? (Wt3 + (size_t)z * HIDN * HIDN) : Wt_o;
    int k0 = blockIdx.x * 32, n0 = blockIdx.y * 32;
    #pragma unroll
    for (int i = 0; i < 32; i += 8)
      tile[ty + i][tx] = src[(size_t)(k0 + ty + i) * HIDN + (n0 + tx)];
    __syncthreads();
    #pragma unroll
    for (int i = 0; i < 32; i += 8)
      dst[(size_t)(n0 + ty + i) * HIDN + (k0 + tx)] = f2bf(tile[tx][ty + i]);
    return;
  }
  int bid = blockIdx.y * 64 + blockIdx.x;
  if (z == 4) {   // cast_hs
    size_t i4 = ((size_t)bid * 256 + tid) * 4;
    float4 v = *(const float4*)&hs[i4];
    ushort4 o;
    o.x = f2bf(v.x); o.y = f2bf(v.y); o.z = f2bf(v.z); o.w = f2bf(v.w);
    *(ushort4*)&hs_bf[i4] = o;
    return;
  }
  // z == 5
  if (bid < 256) {   // rope table
    int i = bid * 256 + tid;
    int pos = i >> 5, f = i & 31;
    float inv = __expf(-(float)f * (9.210340371976184f / 32.0f));
    float ang = (float)pos * inv;
    rope_c[i] = cosf(ang);
    rope_s[i] = sinf(ang);
    return;
  }
  if (bid < 384) {   // chunk_we, chunk c = bid-256
    __shared__ float red[16][17];
    __shared__ float wgt[16];
    int c = bid - 256;
    int row = tid >> 4, seg = tid & 15;
    const float* hrow = hs + ((size_t)c * 16 + row) * HIDN;
    float p = 0.f;
    #pragma unroll 8
    for (int k = seg * 128; k < seg * 128 + 128; k += 4) {
      float4 hv = *(const float4*)&hrow[k];
      float4 wv = *(const float4*)&Wc[k];
      p += hv.x * wv.x + hv.y * wv.y + hv.z * wv.z + hv.w * wv.w;
    }
    red[row][seg] = p;
    __syncthreads();
    if (tid < 16) {
      float lg = 0.f;
      #pragma unroll
      for (int j = 0; j < 16; ++j) lg += red[tid][j];
      lg += bc[0];
      float m = lg;
      #pragma unroll
      for (int msk = 1; msk <= 8; msk <<= 1) m = fmaxf(m, __shfl_xor(m, msk));
      float ev = __expf(lg - m);
      float sum = ev;
      #pragma unroll
      for (int msk = 1; msk <= 8; msk <<= 1) sum += __shfl_xor(sum, msk);
      wgt[tid] = ev / sum;
    }
    __syncthreads();
    #pragma unroll
    for (int j = 0; j < 8; ++j) {
      int hb = tid + j * 256;
      float acc = 0.f;
      #pragma unroll
      for (int r = 0; r < 16; ++r)
        acc += wgt[r] * hs[((size_t)c * 16 + r) * HIDN + hb];
      entries_bf[(size_t)c * HIDN + hb] = f2bf(acc);
    }
    return;
  }
  if (bid < 896) {   // transpose_w
    int idx = bid - 384;
    int zw = idx >> 8, byw = (idx >> 6) & 3, bxw = idx & 63;
    const float* src = zw ? Wv : Wk;
    u16* dst = Wkv_t + (size_t)zw * HDIM * 2048;
    int k0 = bxw * 32, n0 = byw * 32;
    #pragma unroll
    for (int i = 0; i < 32; i += 8)
      tile[ty + i][tx] = src[(size_t)(k0 + ty + i) * HDIM + (n0 + tx)];
    __syncthreads();
    #pragma unroll
    for (int i = 0; i < 32; i += 8)
      dst[(size_t)(n0 + ty + i) * 2048 + (k0 + tx)] = f2bf(tile[tx][ty + i]);
  }
}

// ---------------- 256x256 GEMM for q/lk/lv (+ck/cv block 192), R9 1-barrier pipeline
// R14: quadrant-chunked XCD tile mapping for L2 locality.
__global__ __launch_bounds__(512, 2) void k_gemm256(
    const u16* __restrict__ A, const u16* __restrict__ Wt3,
    const u16* __restrict__ entries_bf, const u16* __restrict__ Wkv_t,
    const float* __restrict__ bq, const float* __restrict__ blk, const float* __restrict__ blv,
    const float* __restrict__ bk, const float* __restrict__ bv,
    const float* __restrict__ qn_w, const float* __restrict__ kn_w,
    const float* __restrict__ rc, const float* __restrict__ rs,
    u16* __restrict__ q_out, u16* __restrict__ lk_out, u16* __restrict__ lv_t,
    u16* __restrict__ ck_bf, u16* __restrict__ cv_t) {
  __shared__ __align__(16) u16 lds[65536];     // 128 KB: 2 x 64 KB
  __shared__ float psq[2][4][128];             // 4 KB
  int tid = threadIdx.x, lane = tid & 63;
  int wid = tid >> 6;
  int wr = wid >> 2, wc = wid & 3;             // 2 x 4 waves
  int lin = blockIdx.x;
  int row0, col0, mode;
  const u16 *Ag, *Bg;
  if (lin < 192) {
    int swz = (lin & 7) * 24 + (lin >> 3);     // XCD-chunked: XCD x gets swz [24x, 24x+24)
    mode = swz >> 6;
    int t = swz & 63;
    int q = t >> 4, u2 = t & 15;               // 4x4 quadrants: compact L2 footprint per chunk
    row0 = ((q & 1) * 4 + (u2 >> 2)) * 256;
    col0 = ((q >> 1) * 4 + (u2 & 3)) * 256;
    Ag = A; Bg = Wt3 + (size_t)mode * HIDN * HIDN;
  } else {
    mode = 3; row0 = 0; col0 = 0;
    Ag = entries_bf; Bg = Wkv_t;
  }
  int rA = lane & 15, kg = lane >> 4;          // kg in [0,4)
  int srow = tid >> 3, sslot = tid & 7;
  int ssl = sslot ^ (srow & 7);                // inverse swizzle on SOURCE slot

  f32x4 acc[8][4];
  #pragma unroll
  for (int m = 0; m < 8; ++m)
    #pragma unroll
    for (int n = 0; n < 4; ++n) acc[m][n] = (f32x4){0.f, 0.f, 0.f, 0.f};

  auto stage = [&](int b, int i, int kt) {
    const u16* src = (i < 4) ? Ag : Bg;
    int rg = ((i < 4) ? row0 : col0) + ((i & 3) * 64) + srow;
    gl_lds16(&src[(size_t)rg * HIDN + kt * 64 + ssl * 8],
             &lds[b * 32768 + i * 4096 + tid * 8]);
  };
  auto rdA = [&](int b, int m, int ks) -> short8 {
    int r = wr * 128 + m * 16 + rA;
    int slot = (ks * 4 + kg) ^ (r & 7);
    return *(const short8*)&lds[b * 32768 + r * 64 + slot * 8];
  };
  auto rdB = [&](int b, int n, int ks) -> short8 {
    int r = wc * 64 + n * 16 + rA;
    int slot = (ks * 4 + kg) ^ (r & 7);
    return *(const short8*)&lds[b * 32768 + 16384 + r * 64 + slot * 8];
  };

  // prologue: tile 0 -> buf 0
  #pragma unroll
  for (int i = 0; i < 8; ++i) stage(0, i, 0);

  short8 Af[4], Bf[4][2];
  for (int u = 0; u < NKT; ++u) {
    int cur = u & 1;
    asm volatile("s_waitcnt vmcnt(0)" ::: "memory");
    __builtin_amdgcn_sched_barrier(0);
    __builtin_amdgcn_s_barrier();
    if (u + 1 < NKT) {
      #pragma unroll
      for (int i = 0; i < 8; ++i) stage(cur ^ 1, i, u + 1);
    }
    #pragma unroll
    for (int n = 0; n < 4; ++n) { Bf[n][0] = rdB(cur, n, 0); Bf[n][1] = rdB(cur, n, 1); }
    // sub-phase 1: A m0-3 ks0
    #pragma unroll
    for (int m = 0; m < 4; ++m) Af[m] = rdA(cur, m, 0);
    asm volatile("s_waitcnt lgkmcnt(0)" ::: "memory");
    __builtin_amdgcn_sched_barrier(0);
    __builtin_amdgcn_s_setprio(1);
    #pragma unroll
    for (int m = 0; m < 4; ++m)
      #pragma unroll
      for (int n = 0; n < 4; ++n)
        acc[m][n] = __builtin_amdgcn_mfma_f32_16x16x32_bf16(Af[m], Bf[n][0], acc[m][n], 0, 0, 0);
    __builtin_amdgcn_s_setprio(0);
    // sub-phase 2: A m0-3 ks1
    #pragma unroll
    for (int m = 0; m < 4; ++m) Af[m] = rdA(cur, m, 1);
    asm volatile("s_waitcnt lgkmcnt(0)" ::: "memory");
    __builtin_amdgcn_sched_barrier(0);
    __builtin_amdgcn_s_setprio(1);
    #pragma unroll
    for (int m = 0; m < 4; ++m)
      #pragma unroll
      for (int n = 0; n < 4; ++n)
        acc[m][n] = __builtin_amdgcn_mfma_f32_16x16x32_bf16(Af[m], Bf[n][1], acc[m][n], 0, 0, 0);
    __builtin_amdgcn_s_setprio(0);
    // sub-phase 3: A m4-7 ks0
    #pragma unroll
    for (int m = 0; m < 4; ++m) Af[m] = rdA(cur, m + 4, 0);
    asm volatile("s_waitcnt lgkmcnt(0)" ::: "memory");
    __builtin_amdgcn_sched_barrier(0);
    __builtin_amdgcn_s_setprio(1);
    #pragma unroll
    for (int m = 0; m < 4; ++m)
      #pragma unroll
      for (int n = 0; n < 4; ++n)
        acc[m + 4][n] = __builtin_amdgcn_mfma_f32_16x16x32_bf16(Af[m], Bf[n][0], acc[m + 4][n], 0, 0, 0);
    __builtin_amdgcn_s_setprio(0);
    // sub-phase 4: A m4-7 ks1
    #pragma unroll
    for (int m = 0; m < 4; ++m) Af[m] = rdA(cur, m + 4, 1);
    asm volatile("s_waitcnt lgkmcnt(0)" ::: "memory");
    __builtin_amdgcn_sched_barrier(0);
    __builtin_amdgcn_s_setprio(1);
    #pragma unroll
    for (int m = 0; m < 4; ++m)
      #pragma unroll
      for (int n = 0; n < 4; ++n)
        acc[m + 4][n] = __builtin_amdgcn_mfma_f32_16x16x32_bf16(Af[m], Bf[n][1], acc[m + 4][n], 0, 0, 0);
    __builtin_amdgcn_s_setprio(0);
  }

  // ---------------- epilogue
  int cl = rA, rbase = kg * 4;
  #pragma unroll
  for (int n = 0; n < 4; ++n) {
    int dl = wc * 64 + n * 16 + cl;
    float bb;
    if (mode == 3)      bb = (dl < 128) ? bk[dl] : bv[dl - 128];
    else if (mode == 0) bb = bq[col0 + dl];
    else if (mode == 1) bb = blk[col0 + dl];
    else                bb = blv[col0 + dl];
    #pragma unroll
    for (int m = 0; m < 8; ++m)
      #pragma unroll
      for (int j = 0; j < 4; ++j) acc[m][n][j] += bb;
  }

  if (mode == 2) {
    int hh = (col0 >> 7) + (wc >> 1);
    #pragma unroll
    for (int m = 0; m < 8; ++m) {
      int sb = row0 + wr * 128 + m * 16 + rbase;
      #pragma unroll
      for (int n = 0; n < 4; ++n) {
        int dl = (wc & 1) * 64 + n * 16 + cl;
        ushort4 o;
        o.x = f2bf(acc[m][n][0]);
        o.y = f2bf(acc[m][n][1]);
        o.z = f2bf(acc[m][n][2]);
        o.w = f2bf(acc[m][n][3]);
        *(ushort4*)&lv_t[((size_t)hh * HDIM + dl) * S_LEN + sb] = o;
      }
    }
    return;
  }

  bool is_cv = (mode == 3) && (wc >= 2);
  if (!is_cv) {
    #pragma unroll
    for (int m = 0; m < 8; ++m)
      #pragma unroll
      for (int j = 0; j < 4; ++j) {
        float s2 = acc[m][0][j] * acc[m][0][j] + acc[m][1][j] * acc[m][1][j]
                 + acc[m][2][j] * acc[m][2][j] + acc[m][3][j] * acc[m][3][j];
        s2 += __shfl_xor(s2, 1); s2 += __shfl_xor(s2, 2);
        s2 += __shfl_xor(s2, 4); s2 += __shfl_xor(s2, 8);
        if (cl == 0) psq[wr][wc][m * 16 + rbase + j] = s2;
      }
  }
  __syncthreads();
  if (is_cv) {
    if (wr == 0) {
      #pragma unroll
      for (int m = 0; m < 8; ++m) {
        int cchunk = m * 16 + rbase;
        #pragma unroll
        for (int n = 0; n < 4; ++n) {
          int d = (wc - 2) * 64 + n * 16 + cl;
          #pragma unroll
          for (int j = 0; j < 4; ++j)
            cv_t[(size_t)d * NCHNK + cchunk + j] = f2bf(acc[m][n][j]);
        }
      }
    }
    return;
  }
  {
    const float* nw = (mode == 0) ? qn_w : kn_w;
    int hgrp = wc >> 1;
    float nwv[4];
    #pragma unroll
    for (int n = 0; n < 4; ++n) nwv[n] = nw[(wc & 1) * 64 + n * 16 + cl];
    #pragma unroll
    for (int m = 0; m < 8; ++m)
      #pragma unroll
      for (int j = 0; j < 4; ++j) {
        int r16 = m * 16 + rbase + j;
        int s = row0 + wr * 128 + r16;
        bool valid = (mode != 3) || (s < NCHNK);
        int sc2 = valid ? s : 0;
        int pos = (mode == 3) ? (sc2 * 16 + 15) : sc2;
        float rr2 = rsqrtf((psq[wr][hgrp * 2][r16] + psq[wr][hgrp * 2 + 1][r16]) * (1.f / 128.f) + 1e-6f);
        float o[4];
        if ((wc & 1) == 0) {
          #pragma unroll
          for (int n = 0; n < 2; ++n) {
            int i = n * 16 + cl;
            float ca = rc[pos * 32 + i], sa = rs[pos * 32 + i];
            float y1 = acc[m][n][j] * rr2 * nwv[n];
            float y2 = acc[m][n + 2][j] * rr2 * nwv[n + 2];
            o[n] = y1 * ca - y2 * sa;
            o[n + 2] = y1 * sa + y2 * ca;
          }
        } else {
          #pragma unroll
          for (int n = 0; n < 4; ++n) o[n] = acc[m][n][j] * rr2 * nwv[n];
        }
        if (valid) {
          u16* dst;
          if (mode == 3) dst = ck_bf + (size_t)s * HDIM + (wc & 1) * 64;
          else {
            u16* dstb = (mode == 0) ? q_out : lk_out;
            dst = dstb + ((size_t)((col0 >> 7) + hgrp) * S_LEN + s) * HDIM + (wc & 1) * 64;
          }
          #pragma unroll
          for (int n = 0; n < 4; ++n) dst[n * 16 + cl] = f2bf(o[n]);
        }
      }
  }
}

// ---------------- out GEMM: pipelined 128^2, counted 1-deep, XCD swizzle
__global__ __launch_bounds__(256, 2) void k_gemm_out(const u16* __restrict__ A, const u16* __restrict__ Bt,
                                                     const float* __restrict__ bias, float* __restrict__ C) {
  __shared__ __align__(16) u16 lds[32768];     // 64 KB: 2 x 32 KB
  int tid = threadIdx.x, lane = tid & 63;
  int wave = tid >> 6;
  int wr = wave >> 1, wc = wave & 1;
  int lin = blockIdx.x + (blockIdx.y << 4);
  int swz = (lin & 7) * 32 + (lin >> 3);       // bijective 256 = 8*32
  int row0 = (swz & 15) * 128, col0 = (swz >> 4) * 128;
  int rA = lane & 15, kg = lane >> 4;
  int srow = tid >> 3, sslot = tid & 7;        // srow in [0,32)
  int ssl = sslot ^ (srow & 7);

  f32x4 acc[4][4];
  #pragma unroll
  for (int m = 0; m < 4; ++m)
    #pragma unroll
    for (int n = 0; n < 4; ++n) acc[m][n] = (f32x4){0.f, 0.f, 0.f, 0.f};

  auto stage = [&](int b, int i, int kt) {
    const u16* src = (i < 4) ? Bt : A;
    int rg = ((i < 4) ? col0 : row0) + (i & 3) * 32 + srow;
    int dofs = (i < 4) ? (8192 + i * 2048) : ((i - 4) * 2048);
    gl_lds16(&src[(size_t)rg * HIDN + kt * 64 + ssl * 8],
             &lds[b * 16384 + dofs + tid * 8]);
  };
  auto rdA = [&](int b, int m, int ks) -> short8 {
    int r = wr * 64 + m * 16 + rA;
    int slot = (ks * 4 + kg) ^ (r & 7);
    return *(const short8*)&lds[b * 16384 + r * 64 + slot * 8];
  };
  auto rdB = [&](int b, int n, int ks) -> short8 {
    int r = wc * 64 + n * 16 + rA;
    int slot = (ks * 4 + kg) ^ (r & 7);
    return *(const short8*)&lds[b * 16384 + 8192 + r * 64 + slot * 8];
  };

  #pragma unroll
  for (int i = 0; i < 8; ++i) stage(0, i, 0);

  short8 Af[4], Bf[4][2];
  for (int u = 0; u < NKT; ++u) {
    int cur = u & 1;
    bool pf = (u + 1 < NKT);
    if (pf) {
      #pragma unroll
      for (int i = 0; i < 8; ++i) stage(cur ^ 1, i, u + 1);
    }
    if (pf) asm volatile("s_waitcnt vmcnt(8)" ::: "memory");
    else    asm volatile("s_waitcnt vmcnt(0)" ::: "memory");
    __builtin_amdgcn_sched_barrier(0);
    __builtin_amdgcn_s_barrier();
    #pragma unroll
    for (int n = 0; n < 4; ++n) { Bf[n][0] = rdB(cur, n, 0); Bf[n][1] = rdB(cur, n, 1); }
    #pragma unroll
    for (int m = 0; m < 4; ++m) Af[m] = rdA(cur, m, 0);
    asm volatile("s_waitcnt lgkmcnt(0)" ::: "memory");
    __builtin_amdgcn_sched_barrier(0);
    __builtin_amdgcn_s_setprio(1);
    #pragma unroll
    for (int m = 0; m < 4; ++m)
      #pragma unroll
      for (int n = 0; n < 4; ++n)
        acc[m][n] = __builtin_amdgcn_mfma_f32_16x16x32_bf16(Af[m], Bf[n][0], acc[m][n], 0, 0, 0);
    __builtin_amdgcn_s_setprio(0);
    #pragma unroll
    for (int m = 0; m < 4; ++m) Af[m] = rdA(cur, m, 1);
    asm volatile("s_waitcnt lgkmcnt(0)" ::: "memory");
    __builtin_amdgcn_sched_barrier(0);
    __builtin_amdgcn_s_setprio(1);
    #pragma unroll
    for (int m = 0; m < 4; ++m)
      #pragma unroll
      for (int n = 0; n < 4; ++n)
        acc[m][n] = __builtin_amdgcn_mfma_f32_16x16x32_bf16(Af[m], Bf[n][1], acc[m][n], 0, 0, 0);
    __builtin_amdgcn_s_setprio(0);
    __builtin_amdgcn_s_barrier();
  }

  int rbase = kg * 4, cl = rA;
  #pragma unroll
  for (int m = 0; m < 4; ++m) {
    int rowb = row0 + wr * 64 + m * 16 + rbase;
    #pragma unroll
    for (int n = 0; n < 4; ++n) {
      int col = col0 + wc * 64 + n * 16 + cl;
      float bb = bias[col];
      #pragma unroll
      for (int j = 0; j < 4; ++j)
        C[(size_t)(rowb + j) * HIDN + col] = acc[m][n][j] + bb;
    }
  }
}

// ---------------- merged attention with T14 async V staging
__global__ __launch_bounds__(256) void k_attn(const u16* __restrict__ q_bf, const u16* __restrict__ ck_bf,
                                              const u16* __restrict__ cv_t, const float* __restrict__ sink_k,
                                              const float* __restrict__ sink_v,
                                              const u16* __restrict__ lk_bf, const u16* __restrict__ lv_t,
                                              u16* __restrict__ merged) {
  __shared__ __align__(16) u16 kv[21760];
  __shared__ __align__(16) float sc[32][164];
  __shared__ __align__(16) u16 pb[32][168];
  int tid = threadIdx.x, lane = tid & 63, wave = tid >> 6;
  int lin = blockIdx.x;
  int sw = (lin & 7) * 128 + (lin >> 3);
  int s0 = (sw & 63) * 32, h = sw >> 6;
  const size_t hb = (size_t)h * S_LEN * HDIM;
  int rA = lane & 15, kg8 = (lane >> 4) * 8;
  int qt = wave & 1, wg = wave >> 1;

  short8 aq[4];
  #pragma unroll
  for (int c = 0; c < 4; ++c)
    aq[c] = *(const short8*)&q_bf[hb + (size_t)(s0 + qt * 16 + rA) * HDIM + c * 32 + kg8];

  // ======== compressed phase ========
  int cmax = s0 / 16 + 2; if (cmax > 128) cmax = 128;
  int nkeys = cmax + 1;
  int nkt = (nkeys + 15) >> 4, nkc = (nkeys + 31) >> 5;

  // T14: issue cv_t loads into registers EARLY (predicated static unroll)
  int dV = tid & 127, halfV = tid >> 7;
  int ng = cmax >> 3;
  const u16* cvrow = cv_t + (size_t)dV * NCHNK;
  uint4 vv[8];
  #pragma unroll
  for (int i = 0; i < 8; ++i) {
    int g = halfV + 2 * i;
    vv[i] = make_uint4(0, 0, 0, 0);
    if (g < ng) vv[i] = *(const uint4*)&cvrow[g * 8];
  }
  float svf = sink_v[h * HDIM + dV];

  for (int i = tid; i < cmax * 16; i += 256) {
    int r = i >> 4, cz = (i & 15) * 8;
    *(uint4*)&kv[r * 136 + cz] = *(const uint4*)&ck_bf[r * HDIM + cz];
  }
  if (tid < 128) kv[cmax * 136 + tid] = f2bf(sink_k[h * HDIM + tid]);
  __syncthreads();

  for (int kt = wg; kt < nkt; kt += 2) {
    f32x4 a = (f32x4){0.f, 0.f, 0.f, 0.f};
    #pragma unroll
    for (int c = 0; c < 4; ++c) {
      short8 bk2 = *(const short8*)&kv[(kt * 16 + rA) * 136 + c * 32 + kg8];
      a = __builtin_amdgcn_mfma_f32_16x16x32_bf16(aq[c], bk2, a, 0, 0, 0);
    }
    int rq = qt * 16 + (lane >> 4) * 4;
    #pragma unroll
    for (int j = 0; j < 4; ++j) sc[rq + j][kt * 16 + rA] = a[j];
  }
  __syncthreads();

  { // softmax (8 lanes / row)
    int ql = tid >> 3, e = tid & 7, s = s0 + ql;
    int NK = nkc * 32;
    float m = -1e30f;
    for (int i = e; i < NK; i += 8) {
      if (i < nkeys) {
        float raw = sc[ql][i];
        bool valid = (i < cmax) ? (i * 16 + 15 <= s) : true;
        float v = valid ? raw * SCALE : -1e9f;
        sc[ql][i] = v;
        m = fmaxf(m, v);
      }
    }
    m = fmaxf(m, __shfl_xor(m, 1));
    m = fmaxf(m, __shfl_xor(m, 2));
    m = fmaxf(m, __shfl_xor(m, 4));
    float sum = 0.f;
    for (int i = e; i < NK; i += 8) {
      if (i < nkeys) {
        float pv = __expf(sc[ql][i] - m);
        sc[ql][i] = pv;
        sum += pv;
      }
    }
    sum += __shfl_xor(sum, 1);
    sum += __shfl_xor(sum, 2);
    sum += __shfl_xor(sum, 4);
    float inv = 1.f / sum;
    for (int i = e; i < NK; i += 8)
      pb[ql][i] = (i < nkeys) ? f2bf(sc[ql][i] * inv) : (u16)0;
  }
  __syncthreads();

  { // write V^T from pre-issued registers + scalar tail
    #pragma unroll
    for (int i = 0; i < 8; ++i) {
      int g = halfV + 2 * i;
      if (g < ng) *(uint4*)&kv[dV * 168 + g * 8] = vv[i];
    }
    u16 sv = f2bf(svf);
    int NC = nkc * 32;
    for (int c = ng * 8 + halfV; c < NC; c += 2) {
      u16 v = (c < cmax) ? cvrow[c] : ((c == cmax) ? sv : (u16)0);
      kv[dV * 168 + c] = v;
    }
  }
  __syncthreads();

  f32x4 po_c[4];
  #pragma unroll
  for (int n = 0; n < 4; ++n) po_c[n] = (f32x4){0.f, 0.f, 0.f, 0.f};
  for (int kc = 0; kc < nkc; ++kc) {
    short8 pfrag = *(const short8*)&pb[qt * 16 + rA][kc * 32 + kg8];
    #pragma unroll
    for (int n = 0; n < 4; ++n) {
      short8 av = *(const short8*)&kv[(wg * 64 + n * 16 + rA) * 168 + kc * 32 + kg8];
      po_c[n] = __builtin_amdgcn_mfma_f32_16x16x32_bf16(av, pfrag, po_c[n], 0, 0, 0);
    }
  }
  __syncthreads();

  // ======== local phase ========
  int tbase = s0 - 128;
  // T14: issue lv_t loads into registers while staging K
  uint4 lvv[10];
  {
    const size_t hbt = (size_t)h * HDIM * S_LEN;
    #pragma unroll
    for (int i = 0; i < 10; ++i) {
      int c8 = halfV + 2 * i;
      int t0 = tbase + c8 * 8;
      lvv[i] = make_uint4(0, 0, 0, 0);
      if (t0 >= 0) lvv[i] = *(const uint4*)&lv_t[hbt + (size_t)dV * S_LEN + t0];
    }
  }
  for (int i = tid; i < 160 * 16; i += 256) {
    int r = i >> 4, cz = (i & 15) * 8;
    int t = tbase + r;
    uint4 val = make_uint4(0, 0, 0, 0);
    if (t >= 0) val = *(const uint4*)&lk_bf[hb + (size_t)t * HDIM + cz];
    *(uint4*)&kv[r * 136 + cz] = val;
  }
  __syncthreads();

  for (int kt = wg; kt < 10; kt += 2) {
    f32x4 a = (f32x4){0.f, 0.f, 0.f, 0.f};
    #pragma unroll
    for (int c = 0; c < 4; ++c) {
      short8 bk2 = *(const short8*)&kv[(kt * 16 + rA) * 136 + c * 32 + kg8];
      a = __builtin_amdgcn_mfma_f32_16x16x32_bf16(aq[c], bk2, a, 0, 0, 0);
    }
    int rq = qt * 16 + (lane >> 4) * 4;
    #pragma unroll
    for (int j = 0; j < 4; ++j) sc[rq + j][kt * 16 + rA] = a[j];
  }
  __syncthreads();

  {
    int ql = tid >> 3, e = tid & 7;
    int ilo = 128 - s0; if (ql > ilo) ilo = ql;
    int ihi = ql + 128;
    float m = -1e30f;
    for (int i = e; i < 160; i += 8) {
      bool valid = (i >= ilo) && (i <= ihi);
      float v = valid ? sc[ql][i] * SCALE : -1e9f;
      sc[ql][i] = v;
      m = fmaxf(m, v);
    }
    m = fmaxf(m, __shfl_xor(m, 1));
    m = fmaxf(m, __shfl_xor(m, 2));
    m = fmaxf(m, __shfl_xor(m, 4));
    float sum = 0.f;
    for (int i = e; i < 160; i += 8) {
      float pv = __expf(sc[ql][i] - m);
      sc[ql][i] = pv;
      sum += pv;
    }
    sum += __shfl_xor(sum, 1);
    sum += __shfl_xor(sum, 2);
    sum += __shfl_xor(sum, 4);
    float inv = 1.f / sum;
    for (int i = e; i < 160; i += 8) pb[ql][i] = f2bf(sc[ql][i] * inv);
  }
  __syncthreads();

  { // write V^T from pre-issued registers
    #pragma unroll
    for (int i = 0; i < 10; ++i) {
      int c8 = halfV + 2 * i;
      *(uint4*)&kv[dV * 168 + c8 * 8] = lvv[i];
    }
  }
  __syncthreads();

  {
    f32x4 po[4];
    #pragma unroll
    for (int n = 0; n < 4; ++n) po[n] = (f32x4){0.f, 0.f, 0.f, 0.f};
    #pragma unroll
    for (int kc = 0; kc < 5; ++kc) {
      short8 pfrag = *(const short8*)&pb[qt * 16 + rA][kc * 32 + kg8];
      #pragma unroll
      for (int n = 0; n < 4; ++n) {
        short8 av = *(const short8*)&kv[(wg * 64 + n * 16 + rA) * 168 + kc * 32 + kg8];
        po[n] = __builtin_amdgcn_mfma_f32_16x16x32_bf16(av, pfrag, po[n], 0, 0, 0);
      }
    }
    int q = qt * 16 + rA;
    int s = s0 + q;
    int rb = (lane >> 4) * 4;
    #pragma unroll
    for (int n = 0; n < 4; ++n) {
      int d0 = wg * 64 + n * 16 + rb;
      ushort4 o;
      o.x = f2bf(0.5f * (po[n][0] + po_c[n][0]));
      o.y = f2bf(0.5f * (po[n][1] + po_c[n][1]));
      o.z = f2bf(0.5f * (po[n][2] + po_c[n][2]));
      o.w = f2bf(0.5f * (po[n][3] + po_c[n][3]));
      *(ushort4*)&merged[(size_t)s * HIDN + h * HDIM + d0] = o;
    }
  }
}

extern "C" void kernel_launch(void* const* d_in, const int* in_sizes, int n_in,
                              void* d_out, int out_size, void* d_ws, size_t ws_size,
                              hipStream_t stream) {
  const float* hs     = (const float*)d_in[0];
  const float* Wq     = (const float*)d_in[1];
  const float* bq     = (const float*)d_in[2];
  const float* Wc     = (const float*)d_in[3];
  const float* bc     = (const float*)d_in[4];
  const float* Wk     = (const float*)d_in[5];
  const float* bk     = (const float*)d_in[6];
  const float* Wv     = (const float*)d_in[7];
  const float* bv     = (const float*)d_in[8];
  const float* Wlk    = (const float*)d_in[9];
  const float* blk    = (const float*)d_in[10];
  const float* Wlv    = (const float*)d_in[11];
  const float* blv    = (const float*)d_in[12];
  const float* qn_w   = (const float*)d_in[13];
  const float* kn_w   = (const float*)d_in[14];
  const float* sink_k = (const float*)d_in[15];
  const float* sink_v = (const float*)d_in[16];
  const float* Wo     = (const float*)d_in[17];
  const float* bo     = (const float*)d_in[18];
  float* out = (float*)d_out;

  char* p = (char*)d_ws;
  auto alloc = [&](size_t bytes) {
    char* r = p;
    p += (bytes + 255) & ~(size_t)255;
    return r;
  };
  float* rope_c  = (float*)alloc((size_t)S_LEN * 32 * 4);
  float* rope_s  = (float*)alloc((size_t)S_LEN * 32 * 4);
  u16*   hs_bf   = (u16*)  alloc((size_t)S_LEN * HIDN * 2);
  u16*   Wt3     = (u16*)  alloc((size_t)3 * HIDN * HIDN * 2);
  u16*   Wt_o    = (u16*)  alloc((size_t)HIDN * HIDN * 2);
  u16*   Wkv_t   = (u16*)  alloc((size_t)2 * HDIM * HIDN * 2);
  u16*   ent_bf  = (u16*)  alloc((size_t)256 * HIDN * 2);
  u16*   q_bf    = (u16*)  alloc((size_t)NHEAD * S_LEN * HDIM * 2);
  u16*   lk_bf   = (u16*)  alloc((size_t)NHEAD * S_LEN * HDIM * 2);
  u16*   lv_t    = (u16*)  alloc((size_t)NHEAD * HDIM * S_LEN * 2);
  u16*   ck_bf   = (u16*)  alloc((size_t)NCHNK * HDIM * 2);
  u16*   cv_t    = (u16*)  alloc((size_t)HDIM * NCHNK * 2);
  u16*   merged  = (u16*)  alloc((size_t)S_LEN * HIDN * 2);
  (void)ws_size; (void)in_sizes; (void)n_in; (void)out_size;

  // all preprocessing in one dispatch
  k_pre<<<dim3(64, 64, 6), dim3(32, 8), 0, stream>>>(Wq, Wlk, Wlv, Wo, hs, Wc, bc, Wk, Wv,
                                                     Wt3, Wt_o, hs_bf, rope_c, rope_s,
                                                     ent_bf, Wkv_t);

  // fused q/lk/lv + ck/cv projections (R9 pipelined 256^2, quadrant-chunked)
  k_gemm256<<<193, 512, 0, stream>>>(hs_bf, Wt3, ent_bf, Wkv_t,
                                     bq, blk, blv, bk, bv, qn_w, kn_w,
                                     rope_c, rope_s, q_bf, lk_bf, lv_t, ck_bf, cv_t);

  // merged attention (compressed + local + merge), XCD-chunked, async V staging
  k_attn<<<1024, 256, 0, stream>>>(q_bf, ck_bf, cv_t, sink_k, sink_v,
                                   lk_bf, lv_t, merged);

  // output projection (pipelined 128^2)
  k_gemm_out<<<dim3(16, 16), 256, 0, stream>>>(merged, Wt_o, bo, out);
}

// Round 15
// 191.448 us; speedup vs baseline: 1.0469x; 1.0213x over previous
//
#include <hip/hip_runtime.h>

// HeavilyCompressedAttention on MI355X (gfx950). R15:
//  - Wo transpose moved from k_pre into k_gemm256's grid (blocks 193-448),
//    hiding it on the 63 CUs idle during the 193-block GEMM.
//  - k_pre: grid (64,64,5) (z==3 Wo slice removed).
//  - everything else byte-identical to R14 (verified, 195.5us).

typedef unsigned short u16;
typedef __attribute__((ext_vector_type(8))) short short8;
typedef __attribute__((ext_vector_type(4))) float f32x4;

#define S_LEN 2048
#define HIDN  2048
#define NHEAD 16
#define HDIM  128
#define NCHNK 128
#define NKT   32                      // K tiles of 64
#define SCALE 0.08838834764831845f   // 1/sqrt(128)

__device__ __forceinline__ float bf2f(u16 h) {
  return __uint_as_float(((unsigned)h) << 16);
}
__device__ __forceinline__ u16 f2bf(float f) {
  unsigned u = __float_as_uint(f);
  unsigned r = (u + 0x7fffu + ((u >> 16) & 1u)) >> 16;
  return (u16)r;
}

typedef __attribute__((address_space(3))) unsigned int lds_uint;
typedef __attribute__((address_space(1))) unsigned int glb_uint;
__device__ __forceinline__ void gl_lds16(const void* g, void* l) {
  __builtin_amdgcn_global_load_lds((glb_uint*)(unsigned long long)g,
                                   (lds_uint*)(unsigned)(unsigned long long)l,
                                   16, 0, 0);
}

// ---------------- fused preprocessing: grid (64,64,5), block (32,8)
//  z 0..2: transpose Wq/Wlk/Wlv; z==3: cast_hs; z==4: rope/chunk_we/transpose_w
__global__ __launch_bounds__(256) void k_pre(
    const float* __restrict__ Wq, const float* __restrict__ Wlk, const float* __restrict__ Wlv,
    const float* __restrict__ hs,
    const float* __restrict__ Wc, const float* __restrict__ bc,
    const float* __restrict__ Wk, const float* __restrict__ Wv,
    u16* __restrict__ Wt3, u16* __restrict__ hs_bf,
    float* __restrict__ rope_c, float* __restrict__ rope_s,
    u16* __restrict__ entries_bf, u16* __restrict__ Wkv_t) {
  __shared__ float tile[32][33];
  int z = blockIdx.z;
  int tx = threadIdx.x, ty = threadIdx.y;
  int tid = ty * 32 + tx;
  if (z < 3) {
    const float* src = (z == 0) ? Wq : (z == 1) ? Wlk : Wlv;
    u16* dst = Wt3 + (size_t)z * HIDN * HIDN;
    int k0 = blockIdx.x * 32, n0 = blockIdx.y * 32;
    #pragma unroll
    for (int i = 0; i < 32; i += 8)
      tile[ty + i][tx] = src[(size_t)(k0 + ty + i) * HIDN + (n0 + tx)];
    __syncthreads();
    #pragma unroll
    for (int i = 0; i < 32; i += 8)
      dst[(size_t)(n0 + ty + i) * HIDN + (k0 + tx)] = f2bf(tile[tx][ty + i]);
    return;
  }
  int bid = blockIdx.y * 64 + blockIdx.x;
  if (z == 3) {   // cast_hs
    size_t i4 = ((size_t)bid * 256 + tid) * 4;
    float4 v = *(const float4*)&hs[i4];
    ushort4 o;
    o.x = f2bf(v.x); o.y = f2bf(v.y); o.z = f2bf(v.z); o.w = f2bf(v.w);
    *(ushort4*)&hs_bf[i4] = o;
    return;
  }
  // z == 4
  if (bid < 256) {   // rope table
    int i = bid * 256 + tid;
    int pos = i >> 5, f = i & 31;
    float inv = __expf(-(float)f * (9.210340371976184f / 32.0f));
    float ang = (float)pos * inv;
    rope_c[i] = cosf(ang);
    rope_s[i] = sinf(ang);
    return;
  }
  if (bid < 384) {   // chunk_we, chunk c = bid-256
    __shared__ float red[16][17];
    __shared__ float wgt[16];
    int c = bid - 256;
    int row = tid >> 4, seg = tid & 15;
    const float* hrow = hs + ((size_t)c * 16 + row) * HIDN;
    float p = 0.f;
    #pragma unroll 8
    for (int k = seg * 128; k < seg * 128 + 128; k += 4) {
      float4 hv = *(const float4*)&hrow[k];
      float4 wv = *(const float4*)&Wc[k];
      p += hv.x * wv.x + hv.y * wv.y + hv.z * wv.z + hv.w * wv.w;
    }
    red[row][seg] = p;
    __syncthreads();
    if (tid < 16) {
      float lg = 0.f;
      #pragma unroll
      for (int j = 0; j < 16; ++j) lg += red[tid][j];
      lg += bc[0];
      float m = lg;
      #pragma unroll
      for (int msk = 1; msk <= 8; msk <<= 1) m = fmaxf(m, __shfl_xor(m, msk));
      float ev = __expf(lg - m);
      float sum = ev;
      #pragma unroll
      for (int msk = 1; msk <= 8; msk <<= 1) sum += __shfl_xor(sum, msk);
      wgt[tid] = ev / sum;
    }
    __syncthreads();
    #pragma unroll
    for (int j = 0; j < 8; ++j) {
      int hb = tid + j * 256;
      float acc = 0.f;
      #pragma unroll
      for (int r = 0; r < 16; ++r)
        acc += wgt[r] * hs[((size_t)c * 16 + r) * HIDN + hb];
      entries_bf[(size_t)c * HIDN + hb] = f2bf(acc);
    }
    return;
  }
  if (bid < 896) {   // transpose_w
    int idx = bid - 384;
    int zw = idx >> 8, byw = (idx >> 6) & 3, bxw = idx & 63;
    const float* src = zw ? Wv : Wk;
    u16* dst = Wkv_t + (size_t)zw * HDIM * 2048;
    int k0 = bxw * 32, n0 = byw * 32;
    #pragma unroll
    for (int i = 0; i < 32; i += 8)
      tile[ty + i][tx] = src[(size_t)(k0 + ty + i) * HDIM + (n0 + tx)];
    __syncthreads();
    #pragma unroll
    for (int i = 0; i < 32; i += 8)
      dst[(size_t)(n0 + ty + i) * 2048 + (k0 + tx)] = f2bf(tile[tx][ty + i]);
  }
}

// ---------------- 256x256 GEMM for q/lk/lv (+ck/cv block 192, +Wo transpose 193-448)
__global__ __launch_bounds__(512, 2) void k_gemm256(
    const u16* __restrict__ A, const u16* __restrict__ Wt3,
    const u16* __restrict__ entries_bf, const u16* __restrict__ Wkv_t,
    const float* __restrict__ Wo, u16* __restrict__ Wt_o,
    const float* __restrict__ bq, const float* __restrict__ blk, const float* __restrict__ blv,
    const float* __restrict__ bk, const float* __restrict__ bv,
    const float* __restrict__ qn_w, const float* __restrict__ kn_w,
    const float* __restrict__ rc, const float* __restrict__ rs,
    u16* __restrict__ q_out, u16* __restrict__ lk_out, u16* __restrict__ lv_t,
    u16* __restrict__ ck_bf, u16* __restrict__ cv_t) {
  __shared__ __align__(16) u16 lds[65536];     // 128 KB: 2 x 64 KB
  __shared__ float psq[2][4][128];             // 4 KB
  int tid = threadIdx.x, lane = tid & 63;
  int wid = tid >> 6;
  int wr = wid >> 2, wc = wid & 3;             // 2 x 4 waves
  int lin = blockIdx.x;

  if (lin >= 193) {   // Wo transpose: 256 blocks x 16 tiles of 32x32 (runs on idle CUs)
    float* tile = (float*)lds;                 // reuse big LDS; [32][33] layout
    int idx = lin - 193;
    int tx = tid & 31, ty8 = tid >> 5;         // 512 thr: ty8 in [0,16)
    for (int j = 0; j < 16; ++j) {
      int t = idx * 16 + j;
      int k0 = (t & 63) * 32, n0 = (t >> 6) * 32;
      tile[ty8 * 33 + tx]        = Wo[(size_t)(k0 + ty8) * HIDN + n0 + tx];
      tile[(ty8 + 16) * 33 + tx] = Wo[(size_t)(k0 + ty8 + 16) * HIDN + n0 + tx];
      __syncthreads();
      Wt_o[(size_t)(n0 + ty8) * HIDN + k0 + tx]        = f2bf(tile[tx * 33 + ty8]);
      Wt_o[(size_t)(n0 + ty8 + 16) * HIDN + k0 + tx]   = f2bf(tile[tx * 33 + ty8 + 16]);
      __syncthreads();
    }
    return;
  }

  int row0, col0, mode;
  const u16 *Ag, *Bg;
  if (lin < 192) {
    int swz = (lin & 7) * 24 + (lin >> 3);     // XCD-chunked: XCD x gets swz [24x, 24x+24)
    mode = swz >> 6;
    int t = swz & 63;
    int q = t >> 4, u2 = t & 15;               // 4x4 quadrants
    row0 = ((q & 1) * 4 + (u2 >> 2)) * 256;
    col0 = ((q >> 1) * 4 + (u2 & 3)) * 256;
    Ag = A; Bg = Wt3 + (size_t)mode * HIDN * HIDN;
  } else {
    mode = 3; row0 = 0; col0 = 0;
    Ag = entries_bf; Bg = Wkv_t;
  }
  int rA = lane & 15, kg = lane >> 4;          // kg in [0,4)
  int srow = tid >> 3, sslot = tid & 7;
  int ssl = sslot ^ (srow & 7);                // inverse swizzle on SOURCE slot

  f32x4 acc[8][4];
  #pragma unroll
  for (int m = 0; m < 8; ++m)
    #pragma unroll
    for (int n = 0; n < 4; ++n) acc[m][n] = (f32x4){0.f, 0.f, 0.f, 0.f};

  auto stage = [&](int b, int i, int kt) {
    const u16* src = (i < 4) ? Ag : Bg;
    int rg = ((i < 4) ? row0 : col0) + ((i & 3) * 64) + srow;
    gl_lds16(&src[(size_t)rg * HIDN + kt * 64 + ssl * 8],
             &lds[b * 32768 + i * 4096 + tid * 8]);
  };
  auto rdA = [&](int b, int m, int ks) -> short8 {
    int r = wr * 128 + m * 16 + rA;
    int slot = (ks * 4 + kg) ^ (r & 7);
    return *(const short8*)&lds[b * 32768 + r * 64 + slot * 8];
  };
  auto rdB = [&](int b, int n, int ks) -> short8 {
    int r = wc * 64 + n * 16 + rA;
    int slot = (ks * 4 + kg) ^ (r & 7);
    return *(const short8*)&lds[b * 32768 + 16384 + r * 64 + slot * 8];
  };

  // prologue: tile 0 -> buf 0
  #pragma unroll
  for (int i = 0; i < 8; ++i) stage(0, i, 0);

  short8 Af[4], Bf[4][2];
  for (int u = 0; u < NKT; ++u) {
    int cur = u & 1;
    asm volatile("s_waitcnt vmcnt(0)" ::: "memory");
    __builtin_amdgcn_sched_barrier(0);
    __builtin_amdgcn_s_barrier();
    if (u + 1 < NKT) {
      #pragma unroll
      for (int i = 0; i < 8; ++i) stage(cur ^ 1, i, u + 1);
    }
    #pragma unroll
    for (int n = 0; n < 4; ++n) { Bf[n][0] = rdB(cur, n, 0); Bf[n][1] = rdB(cur, n, 1); }
    // sub-phase 1: A m0-3 ks0
    #pragma unroll
    for (int m = 0; m < 4; ++m) Af[m] = rdA(cur, m, 0);
    asm volatile("s_waitcnt lgkmcnt(0)" ::: "memory");
    __builtin_amdgcn_sched_barrier(0);
    __builtin_amdgcn_s_setprio(1);
    #pragma unroll
    for (int m = 0; m < 4; ++m)
      #pragma unroll
      for (int n = 0; n < 4; ++n)
        acc[m][n] = __builtin_amdgcn_mfma_f32_16x16x32_bf16(Af[m], Bf[n][0], acc[m][n], 0, 0, 0);
    __builtin_amdgcn_s_setprio(0);
    // sub-phase 2: A m0-3 ks1
    #pragma unroll
    for (int m = 0; m < 4; ++m) Af[m] = rdA(cur, m, 1);
    asm volatile("s_waitcnt lgkmcnt(0)" ::: "memory");
    __builtin_amdgcn_sched_barrier(0);
    __builtin_amdgcn_s_setprio(1);
    #pragma unroll
    for (int m = 0; m < 4; ++m)
      #pragma unroll
      for (int n = 0; n < 4; ++n)
        acc[m][n] = __builtin_amdgcn_mfma_f32_16x16x32_bf16(Af[m], Bf[n][1], acc[m][n], 0, 0, 0);
    __builtin_amdgcn_s_setprio(0);
    // sub-phase 3: A m4-7 ks0
    #pragma unroll
    for (int m = 0; m < 4; ++m) Af[m] = rdA(cur, m + 4, 0);
    asm volatile("s_waitcnt lgkmcnt(0)" ::: "memory");
    __builtin_amdgcn_sched_barrier(0);
    __builtin_amdgcn_s_setprio(1);
    #pragma unroll
    for (int m = 0; m < 4; ++m)
      #pragma unroll
      for (int n = 0; n < 4; ++n)
        acc[m + 4][n] = __builtin_amdgcn_mfma_f32_16x16x32_bf16(Af[m], Bf[n][0], acc[m + 4][n], 0, 0, 0);
    __builtin_amdgcn_s_setprio(0);
    // sub-phase 4: A m4-7 ks1
    #pragma unroll
    for (int m = 0; m < 4; ++m) Af[m] = rdA(cur, m + 4, 1);
    asm volatile("s_waitcnt lgkmcnt(0)" ::: "memory");
    __builtin_amdgcn_sched_barrier(0);
    __builtin_amdgcn_s_setprio(1);
    #pragma unroll
    for (int m = 0; m < 4; ++m)
      #pragma unroll
      for (int n = 0; n < 4; ++n)
        acc[m + 4][n] = __builtin_amdgcn_mfma_f32_16x16x32_bf16(Af[m], Bf[n][1], acc[m + 4][n], 0, 0, 0);
    __builtin_amdgcn_s_setprio(0);
  }

  // ---------------- epilogue
  int cl = rA, rbase = kg * 4;
  #pragma unroll
  for (int n = 0; n < 4; ++n) {
    int dl = wc * 64 + n * 16 + cl;
    float bb;
    if (mode == 3)      bb = (dl < 128) ? bk[dl] : bv[dl - 128];
    else if (mode == 0) bb = bq[col0 + dl];
    else if (mode == 1) bb = blk[col0 + dl];
    else                bb = blv[col0 + dl];
    #pragma unroll
    for (int m = 0; m < 8; ++m)
      #pragma unroll
      for (int j = 0; j < 4; ++j) acc[m][n][j] += bb;
  }

  if (mode == 2) {
    int hh = (col0 >> 7) + (wc >> 1);
    #pragma unroll
    for (int m = 0; m < 8; ++m) {
      int sb = row0 + wr * 128 + m * 16 + rbase;
      #pragma unroll
      for (int n = 0; n < 4; ++n) {
        int dl = (wc & 1) * 64 + n * 16 + cl;
        ushort4 o;
        o.x = f2bf(acc[m][n][0]);
        o.y = f2bf(acc[m][n][1]);
        o.z = f2bf(acc[m][n][2]);
        o.w = f2bf(acc[m][n][3]);
        *(ushort4*)&lv_t[((size_t)hh * HDIM + dl) * S_LEN + sb] = o;
      }
    }
    return;
  }

  bool is_cv = (mode == 3) && (wc >= 2);
  if (!is_cv) {
    #pragma unroll
    for (int m = 0; m < 8; ++m)
      #pragma unroll
      for (int j = 0; j < 4; ++j) {
        float s2 = acc[m][0][j] * acc[m][0][j] + acc[m][1][j] * acc[m][1][j]
                 + acc[m][2][j] * acc[m][2][j] + acc[m][3][j] * acc[m][3][j];
        s2 += __shfl_xor(s2, 1); s2 += __shfl_xor(s2, 2);
        s2 += __shfl_xor(s2, 4); s2 += __shfl_xor(s2, 8);
        if (cl == 0) psq[wr][wc][m * 16 + rbase + j] = s2;
      }
  }
  __syncthreads();
  if (is_cv) {
    if (wr == 0) {
      #pragma unroll
      for (int m = 0; m < 8; ++m) {
        int cchunk = m * 16 + rbase;
        #pragma unroll
        for (int n = 0; n < 4; ++n) {
          int d = (wc - 2) * 64 + n * 16 + cl;
          #pragma unroll
          for (int j = 0; j < 4; ++j)
            cv_t[(size_t)d * NCHNK + cchunk + j] = f2bf(acc[m][n][j]);
        }
      }
    }
    return;
  }
  {
    const float* nw = (mode == 0) ? qn_w : kn_w;
    int hgrp = wc >> 1;
    float nwv[4];
    #pragma unroll
    for (int n = 0; n < 4; ++n) nwv[n] = nw[(wc & 1) * 64 + n * 16 + cl];
    #pragma unroll
    for (int m = 0; m < 8; ++m)
      #pragma unroll
      for (int j = 0; j < 4; ++j) {
        int r16 = m * 16 + rbase + j;
        int s = row0 + wr * 128 + r16;
        bool valid = (mode != 3) || (s < NCHNK);
        int sc2 = valid ? s : 0;
        int pos = (mode == 3) ? (sc2 * 16 + 15) : sc2;
        float rr2 = rsqrtf((psq[wr][hgrp * 2][r16] + psq[wr][hgrp * 2 + 1][r16]) * (1.f / 128.f) + 1e-6f);
        float o[4];
        if ((wc & 1) == 0) {
          #pragma unroll
          for (int n = 0; n < 2; ++n) {
            int i = n * 16 + cl;
            float ca = rc[pos * 32 + i], sa = rs[pos * 32 + i];
            float y1 = acc[m][n][j] * rr2 * nwv[n];
            float y2 = acc[m][n + 2][j] * rr2 * nwv[n + 2];
            o[n] = y1 * ca - y2 * sa;
            o[n + 2] = y1 * sa + y2 * ca;
          }
        } else {
          #pragma unroll
          for (int n = 0; n < 4; ++n) o[n] = acc[m][n][j] * rr2 * nwv[n];
        }
        if (valid) {
          u16* dst;
          if (mode == 3) dst = ck_bf + (size_t)s * HDIM + (wc & 1) * 64;
          else {
            u16* dstb = (mode == 0) ? q_out : lk_out;
            dst = dstb + ((size_t)((col0 >> 7) + hgrp) * S_LEN + s) * HDIM + (wc & 1) * 64;
          }
          #pragma unroll
          for (int n = 0; n < 4; ++n) dst[n * 16 + cl] = f2bf(o[n]);
        }
      }
  }
}

// ---------------- out GEMM: pipelined 128^2, counted 1-deep, XCD swizzle
__global__ __launch_bounds__(256, 2) void k_gemm_out(const u16* __restrict__ A, const u16* __restrict__ Bt,
                                                     const float* __restrict__ bias, float* __restrict__ C) {
  __shared__ __align__(16) u16 lds[32768];     // 64 KB: 2 x 32 KB
  int tid = threadIdx.x, lane = tid & 63;
  int wave = tid >> 6;
  int wr = wave >> 1, wc = wave & 1;
  int lin = blockIdx.x + (blockIdx.y << 4);
  int swz = (lin & 7) * 32 + (lin >> 3);       // bijective 256 = 8*32
  int row0 = (swz & 15) * 128, col0 = (swz >> 4) * 128;
  int rA = lane & 15, kg = lane >> 4;
  int srow = tid >> 3, sslot = tid & 7;        // srow in [0,32)
  int ssl = sslot ^ (srow & 7);

  f32x4 acc[4][4];
  #pragma unroll
  for (int m = 0; m < 4; ++m)
    #pragma unroll
    for (int n = 0; n < 4; ++n) acc[m][n] = (f32x4){0.f, 0.f, 0.f, 0.f};

  auto stage = [&](int b, int i, int kt) {
    const u16* src = (i < 4) ? Bt : A;
    int rg = ((i < 4) ? col0 : row0) + (i & 3) * 32 + srow;
    int dofs = (i < 4) ? (8192 + i * 2048) : ((i - 4) * 2048);
    gl_lds16(&src[(size_t)rg * HIDN + kt * 64 + ssl * 8],
             &lds[b * 16384 + dofs + tid * 8]);
  };
  auto rdA = [&](int b, int m, int ks) -> short8 {
    int r = wr * 64 + m * 16 + rA;
    int slot = (ks * 4 + kg) ^ (r & 7);
    return *(const short8*)&lds[b * 16384 + r * 64 + slot * 8];
  };
  auto rdB = [&](int b, int n, int ks) -> short8 {
    int r = wc * 64 + n * 16 + rA;
    int slot = (ks * 4 + kg) ^ (r & 7);
    return *(const short8*)&lds[b * 16384 + 8192 + r * 64 + slot * 8];
  };

  #pragma unroll
  for (int i = 0; i < 8; ++i) stage(0, i, 0);

  short8 Af[4], Bf[4][2];
  for (int u = 0; u < NKT; ++u) {
    int cur = u & 1;
    bool pf = (u + 1 < NKT);
    if (pf) {
      #pragma unroll
      for (int i = 0; i < 8; ++i) stage(cur ^ 1, i, u + 1);
    }
    if (pf) asm volatile("s_waitcnt vmcnt(8)" ::: "memory");
    else    asm volatile("s_waitcnt vmcnt(0)" ::: "memory");
    __builtin_amdgcn_sched_barrier(0);
    __builtin_amdgcn_s_barrier();
    #pragma unroll
    for (int n = 0; n < 4; ++n) { Bf[n][0] = rdB(cur, n, 0); Bf[n][1] = rdB(cur, n, 1); }
    #pragma unroll
    for (int m = 0; m < 4; ++m) Af[m] = rdA(cur, m, 0);
    asm volatile("s_waitcnt lgkmcnt(0)" ::: "memory");
    __builtin_amdgcn_sched_barrier(0);
    __builtin_amdgcn_s_setprio(1);
    #pragma unroll
    for (int m = 0; m < 4; ++m)
      #pragma unroll
      for (int n = 0; n < 4; ++n)
        acc[m][n] = __builtin_amdgcn_mfma_f32_16x16x32_bf16(Af[m], Bf[n][0], acc[m][n], 0, 0, 0);
    __builtin_amdgcn_s_setprio(0);
    #pragma unroll
    for (int m = 0; m < 4; ++m) Af[m] = rdA(cur, m, 1);
    asm volatile("s_waitcnt lgkmcnt(0)" ::: "memory");
    __builtin_amdgcn_sched_barrier(0);
    __builtin_amdgcn_s_setprio(1);
    #pragma unroll
    for (int m = 0; m < 4; ++m)
      #pragma unroll
      for (int n = 0; n < 4; ++n)
        acc[m][n] = __builtin_amdgcn_mfma_f32_16x16x32_bf16(Af[m], Bf[n][1], acc[m][n], 0, 0, 0);
    __builtin_amdgcn_s_setprio(0);
    __builtin_amdgcn_s_barrier();
  }

  int rbase = kg * 4, cl = rA;
  #pragma unroll
  for (int m = 0; m < 4; ++m) {
    int rowb = row0 + wr * 64 + m * 16 + rbase;
    #pragma unroll
    for (int n = 0; n < 4; ++n) {
      int col = col0 + wc * 64 + n * 16 + cl;
      float bb = bias[col];
      #pragma unroll
      for (int j = 0; j < 4; ++j)
        C[(size_t)(rowb + j) * HIDN + col] = acc[m][n][j] + bb;
    }
  }
}

// ---------------- merged attention with T14 async V staging
__global__ __launch_bounds__(256) void k_attn(const u16* __restrict__ q_bf, const u16* __restrict__ ck_bf,
                                              const u16* __restrict__ cv_t, const float* __restrict__ sink_k,
                                              const float* __restrict__ sink_v,
                                              const u16* __restrict__ lk_bf, const u16* __restrict__ lv_t,
                                              u16* __restrict__ merged) {
  __shared__ __align__(16) u16 kv[21760];
  __shared__ __align__(16) float sc[32][164];
  __shared__ __align__(16) u16 pb[32][168];
  int tid = threadIdx.x, lane = tid & 63, wave = tid >> 6;
  int lin = blockIdx.x;
  int sw = (lin & 7) * 128 + (lin >> 3);
  int s0 = (sw & 63) * 32, h = sw >> 6;
  const size_t hb = (size_t)h * S_LEN * HDIM;
  int rA = lane & 15, kg8 = (lane >> 4) * 8;
  int qt = wave & 1, wg = wave >> 1;

  short8 aq[4];
  #pragma unroll
  for (int c = 0; c < 4; ++c)
    aq[c] = *(const short8*)&q_bf[hb + (size_t)(s0 + qt * 16 + rA) * HDIM + c * 32 + kg8];

  // ======== compressed phase ========
  int cmax = s0 / 16 + 2; if (cmax > 128) cmax = 128;
  int nkeys = cmax + 1;
  int nkt = (nkeys + 15) >> 4, nkc = (nkeys + 31) >> 5;

  // T14: issue cv_t loads into registers EARLY (predicated static unroll)
  int dV = tid & 127, halfV = tid >> 7;
  int ng = cmax >> 3;
  const u16* cvrow = cv_t + (size_t)dV * NCHNK;
  uint4 vv[8];
  #pragma unroll
  for (int i = 0; i < 8; ++i) {
    int g = halfV + 2 * i;
    vv[i] = make_uint4(0, 0, 0, 0);
    if (g < ng) vv[i] = *(const uint4*)&cvrow[g * 8];
  }
  float svf = sink_v[h * HDIM + dV];

  for (int i = tid; i < cmax * 16; i += 256) {
    int r = i >> 4, cz = (i & 15) * 8;
    *(uint4*)&kv[r * 136 + cz] = *(const uint4*)&ck_bf[r * HDIM + cz];
  }
  if (tid < 128) kv[cmax * 136 + tid] = f2bf(sink_k[h * HDIM + tid]);
  __syncthreads();

  for (int kt = wg; kt < nkt; kt += 2) {
    f32x4 a = (f32x4){0.f, 0.f, 0.f, 0.f};
    #pragma unroll
    for (int c = 0; c < 4; ++c) {
      short8 bk2 = *(const short8*)&kv[(kt * 16 + rA) * 136 + c * 32 + kg8];
      a = __builtin_amdgcn_mfma_f32_16x16x32_bf16(aq[c], bk2, a, 0, 0, 0);
    }
    int rq = qt * 16 + (lane >> 4) * 4;
    #pragma unroll
    for (int j = 0; j < 4; ++j) sc[rq + j][kt * 16 + rA] = a[j];
  }
  __syncthreads();

  { // softmax (8 lanes / row)
    int ql = tid >> 3, e = tid & 7, s = s0 + ql;
    int NK = nkc * 32;
    float m = -1e30f;
    for (int i = e; i < NK; i += 8) {
      if (i < nkeys) {
        float raw = sc[ql][i];
        bool valid = (i < cmax) ? (i * 16 + 15 <= s) : true;
        float v = valid ? raw * SCALE : -1e9f;
        sc[ql][i] = v;
        m = fmaxf(m, v);
      }
    }
    m = fmaxf(m, __shfl_xor(m, 1));
    m = fmaxf(m, __shfl_xor(m, 2));
    m = fmaxf(m, __shfl_xor(m, 4));
    float sum = 0.f;
    for (int i = e; i < NK; i += 8) {
      if (i < nkeys) {
        float pv = __expf(sc[ql][i] - m);
        sc[ql][i] = pv;
        sum += pv;
      }
    }
    sum += __shfl_xor(sum, 1);
    sum += __shfl_xor(sum, 2);
    sum += __shfl_xor(sum, 4);
    float inv = 1.f / sum;
    for (int i = e; i < NK; i += 8)
      pb[ql][i] = (i < nkeys) ? f2bf(sc[ql][i] * inv) : (u16)0;
  }
  __syncthreads();

  { // write V^T from pre-issued registers + scalar tail
    #pragma unroll
    for (int i = 0; i < 8; ++i) {
      int g = halfV + 2 * i;
      if (g < ng) *(uint4*)&kv[dV * 168 + g * 8] = vv[i];
    }
    u16 sv = f2bf(svf);
    int NC = nkc * 32;
    for (int c = ng * 8 + halfV; c < NC; c += 2) {
      u16 v = (c < cmax) ? cvrow[c] : ((c == cmax) ? sv : (u16)0);
      kv[dV * 168 + c] = v;
    }
  }
  __syncthreads();

  f32x4 po_c[4];
  #pragma unroll
  for (int n = 0; n < 4; ++n) po_c[n] = (f32x4){0.f, 0.f, 0.f, 0.f};
  for (int kc = 0; kc < nkc; ++kc) {
    short8 pfrag = *(const short8*)&pb[qt * 16 + rA][kc * 32 + kg8];
    #pragma unroll
    for (int n = 0; n < 4; ++n) {
      short8 av = *(const short8*)&kv[(wg * 64 + n * 16 + rA) * 168 + kc * 32 + kg8];
      po_c[n] = __builtin_amdgcn_mfma_f32_16x16x32_bf16(av, pfrag, po_c[n], 0, 0, 0);
    }
  }
  __syncthreads();

  // ======== local phase ========
  int tbase = s0 - 128;
  // T14: issue lv_t loads into registers while staging K
  uint4 lvv[10];
  {
    const size_t hbt = (size_t)h * HDIM * S_LEN;
    #pragma unroll
    for (int i = 0; i < 10; ++i) {
      int c8 = halfV + 2 * i;
      int t0 = tbase + c8 * 8;
      lvv[i] = make_uint4(0, 0, 0, 0);
      if (t0 >= 0) lvv[i] = *(const uint4*)&lv_t[hbt + (size_t)dV * S_LEN + t0];
    }
  }
  for (int i = tid; i < 160 * 16; i += 256) {
    int r = i >> 4, cz = (i & 15) * 8;
    int t = tbase + r;
    uint4 val = make_uint4(0, 0, 0, 0);
    if (t >= 0) val = *(const uint4*)&lk_bf[hb + (size_t)t * HDIM + cz];
    *(uint4*)&kv[r * 136 + cz] = val;
  }
  __syncthreads();

  for (int kt = wg; kt < 10; kt += 2) {
    f32x4 a = (f32x4){0.f, 0.f, 0.f, 0.f};
    #pragma unroll
    for (int c = 0; c < 4; ++c) {
      short8 bk2 = *(const short8*)&kv[(kt * 16 + rA) * 136 + c * 32 + kg8];
      a = __builtin_amdgcn_mfma_f32_16x16x32_bf16(aq[c], bk2, a, 0, 0, 0);
    }
    int rq = qt * 16 + (lane >> 4) * 4;
    #pragma unroll
    for (int j = 0; j < 4; ++j) sc[rq + j][kt * 16 + rA] = a[j];
  }
  __syncthreads();

  {
    int ql = tid >> 3, e = tid & 7;
    int ilo = 128 - s0; if (ql > ilo) ilo = ql;
    int ihi = ql + 128;
    float m = -1e30f;
    for (int i = e; i < 160; i += 8) {
      bool valid = (i >= ilo) && (i <= ihi);
      float v = valid ? sc[ql][i] * SCALE : -1e9f;
      sc[ql][i] = v;
      m = fmaxf(m, v);
    }
    m = fmaxf(m, __shfl_xor(m, 1));
    m = fmaxf(m, __shfl_xor(m, 2));
    m = fmaxf(m, __shfl_xor(m, 4));
    float sum = 0.f;
    for (int i = e; i < 160; i += 8) {
      float pv = __expf(sc[ql][i] - m);
      sc[ql][i] = pv;
      sum += pv;
    }
    sum += __shfl_xor(sum, 1);
    sum += __shfl_xor(sum, 2);
    sum += __shfl_xor(sum, 4);
    float inv = 1.f / sum;
    for (int i = e; i < 160; i += 8) pb[ql][i] = f2bf(sc[ql][i] * inv);
  }
  __syncthreads();

  { // write V^T from pre-issued registers
    #pragma unroll
    for (int i = 0; i < 10; ++i) {
      int c8 = halfV + 2 * i;
      *(uint4*)&kv[dV * 168 + c8 * 8] = lvv[i];
    }
  }
  __syncthreads();

  {
    f32x4 po[4];
    #pragma unroll
    for (int n = 0; n < 4; ++n) po[n] = (f32x4){0.f, 0.f, 0.f, 0.f};
    #pragma unroll
    for (int kc = 0; kc < 5; ++kc) {
      short8 pfrag = *(const short8*)&pb[qt * 16 + rA][kc * 32 + kg8];
      #pragma unroll
      for (int n = 0; n < 4; ++n) {
        short8 av = *(const short8*)&kv[(wg * 64 + n * 16 + rA) * 168 + kc * 32 + kg8];
        po[n] = __builtin_amdgcn_mfma_f32_16x16x32_bf16(av, pfrag, po[n], 0, 0, 0);
      }
    }
    int q = qt * 16 + rA;
    int s = s0 + q;
    int rb = (lane >> 4) * 4;
    #pragma unroll
    for (int n = 0; n < 4; ++n) {
      int d0 = wg * 64 + n * 16 + rb;
      ushort4 o;
      o.x = f2bf(0.5f * (po[n][0] + po_c[n][0]));
      o.y = f2bf(0.5f * (po[n][1] + po_c[n][1]));
      o.z = f2bf(0.5f * (po[n][2] + po_c[n][2]));
      o.w = f2bf(0.5f * (po[n][3] + po_c[n][3]));
      *(ushort4*)&merged[(size_t)s * HIDN + h * HDIM + d0] = o;
    }
  }
}

extern "C" void kernel_launch(void* const* d_in, const int* in_sizes, int n_in,
                              void* d_out, int out_size, void* d_ws, size_t ws_size,
                              hipStream_t stream) {
  const float* hs     = (const float*)d_in[0];
  const float* Wq     = (const float*)d_in[1];
  const float* bq     = (const float*)d_in[2];
  const float* Wc     = (const float*)d_in[3];
  const float* bc     = (const float*)d_in[4];
  const float* Wk     = (const float*)d_in[5];
  const float* bk     = (const float*)d_in[6];
  const float* Wv     = (const float*)d_in[7];
  const float* bv     = (const float*)d_in[8];
  const float* Wlk    = (const float*)d_in[9];
  const float* blk    = (const float*)d_in[10];
  const float* Wlv    = (const float*)d_in[11];
  const float* blv    = (const float*)d_in[12];
  const float* qn_w   = (const float*)d_in[13];
  const float* kn_w   = (const float*)d_in[14];
  const float* sink_k = (const float*)d_in[15];
  const float* sink_v = (const float*)d_in[16];
  const float* Wo     = (const float*)d_in[17];
  const float* bo     = (const float*)d_in[18];
  float* out = (float*)d_out;

  char* p = (char*)d_ws;
  auto alloc = [&](size_t bytes) {
    char* r = p;
    p += (bytes + 255) & ~(size_t)255;
    return r;
  };
  float* rope_c  = (float*)alloc((size_t)S_LEN * 32 * 4);
  float* rope_s  = (float*)alloc((size_t)S_LEN * 32 * 4);
  u16*   hs_bf   = (u16*)  alloc((size_t)S_LEN * HIDN * 2);
  u16*   Wt3     = (u16*)  alloc((size_t)3 * HIDN * HIDN * 2);
  u16*   Wt_o    = (u16*)  alloc((size_t)HIDN * HIDN * 2);
  u16*   Wkv_t   = (u16*)  alloc((size_t)2 * HDIM * HIDN * 2);
  u16*   ent_bf  = (u16*)  alloc((size_t)256 * HIDN * 2);
  u16*   q_bf    = (u16*)  alloc((size_t)NHEAD * S_LEN * HDIM * 2);
  u16*   lk_bf   = (u16*)  alloc((size_t)NHEAD * S_LEN * HDIM * 2);
  u16*   lv_t    = (u16*)  alloc((size_t)NHEAD * HDIM * S_LEN * 2);
  u16*   ck_bf   = (u16*)  alloc((size_t)NCHNK * HDIM * 2);
  u16*   cv_t    = (u16*)  alloc((size_t)HDIM * NCHNK * 2);
  u16*   merged  = (u16*)  alloc((size_t)S_LEN * HIDN * 2);
  (void)ws_size; (void)in_sizes; (void)n_in; (void)out_size;

  // preprocessing (Wo transpose moved into k_gemm256)
  k_pre<<<dim3(64, 64, 5), dim3(32, 8), 0, stream>>>(Wq, Wlk, Wlv, hs, Wc, bc, Wk, Wv,
                                                     Wt3, hs_bf, rope_c, rope_s,
                                                     ent_bf, Wkv_t);

  // fused q/lk/lv + ck/cv projections + Wo transpose on idle CUs
  k_gemm256<<<449, 512, 0, stream>>>(hs_bf, Wt3, ent_bf, Wkv_t, Wo, Wt_o,
                                     bq, blk, blv, bk, bv, qn_w, kn_w,
                                     rope_c, rope_s, q_bf, lk_bf, lv_t, ck_bf, cv_t);

  // merged attention (compressed + local + merge), XCD-chunked, async V staging
  k_attn<<<1024, 256, 0, stream>>>(q_bf, ck_bf, cv_t, sink_k, sink_v,
                                   lk_bf, lv_t, merged);

  // output projection (pipelined 128^2)
  k_gemm_out<<<dim3(16, 16), 256, 0, stream>>>(merged, Wt_o, bo, out);
}

// Round 16
// 191.405 us; speedup vs baseline: 1.0472x; 1.0002x over previous
//
#include <hip/hip_runtime.h>

// HeavilyCompressedAttention on MI355X (gfx950). R16:
//  - Wo transpose resized to exactly 63 blocks (lin 193-255), 66 tiles each,
//    so all transpose work is co-resident with the 193 GEMM blocks (no tail).
//  - everything else byte-identical to R15 (verified, 191.4us).

typedef unsigned short u16;
typedef __attribute__((ext_vector_type(8))) short short8;
typedef __attribute__((ext_vector_type(4))) float f32x4;

#define S_LEN 2048
#define HIDN  2048
#define NHEAD 16
#define HDIM  128
#define NCHNK 128
#define NKT   32                      // K tiles of 64
#define SCALE 0.08838834764831845f   // 1/sqrt(128)

__device__ __forceinline__ float bf2f(u16 h) {
  return __uint_as_float(((unsigned)h) << 16);
}
__device__ __forceinline__ u16 f2bf(float f) {
  unsigned u = __float_as_uint(f);
  unsigned r = (u + 0x7fffu + ((u >> 16) & 1u)) >> 16;
  return (u16)r;
}

typedef __attribute__((address_space(3))) unsigned int lds_uint;
typedef __attribute__((address_space(1))) unsigned int glb_uint;
__device__ __forceinline__ void gl_lds16(const void* g, void* l) {
  __builtin_amdgcn_global_load_lds((glb_uint*)(unsigned long long)g,
                                   (lds_uint*)(unsigned)(unsigned long long)l,
                                   16, 0, 0);
}

// ---------------- fused preprocessing: grid (64,64,5), block (32,8)
//  z 0..2: transpose Wq/Wlk/Wlv; z==3: cast_hs; z==4: rope/chunk_we/transpose_w
__global__ __launch_bounds__(256) void k_pre(
    const float* __restrict__ Wq, const float* __restrict__ Wlk, const float* __restrict__ Wlv,
    const float* __restrict__ hs,
    const float* __restrict__ Wc, const float* __restrict__ bc,
    const float* __restrict__ Wk, const float* __restrict__ Wv,
    u16* __restrict__ Wt3, u16* __restrict__ hs_bf,
    float* __restrict__ rope_c, float* __restrict__ rope_s,
    u16* __restrict__ entries_bf, u16* __restrict__ Wkv_t) {
  __shared__ float tile[32][33];
  int z = blockIdx.z;
  int tx = threadIdx.x, ty = threadIdx.y;
  int tid = ty * 32 + tx;
  if (z < 3) {
    const float* src = (z == 0) ? Wq : (z == 1) ? Wlk : Wlv;
    u16* dst = Wt3 + (size_t)z * HIDN * HIDN;
    int k0 = blockIdx.x * 32, n0 = blockIdx.y * 32;
    #pragma unroll
    for (int i = 0; i < 32; i += 8)
      tile[ty + i][tx] = src[(size_t)(k0 + ty + i) * HIDN + (n0 + tx)];
    __syncthreads();
    #pragma unroll
    for (int i = 0; i < 32; i += 8)
      dst[(size_t)(n0 + ty + i) * HIDN + (k0 + tx)] = f2bf(tile[tx][ty + i]);
    return;
  }
  int bid = blockIdx.y * 64 + blockIdx.x;
  if (z == 3) {   // cast_hs
    size_t i4 = ((size_t)bid * 256 + tid) * 4;
    float4 v = *(const float4*)&hs[i4];
    ushort4 o;
    o.x = f2bf(v.x); o.y = f2bf(v.y); o.z = f2bf(v.z); o.w = f2bf(v.w);
    *(ushort4*)&hs_bf[i4] = o;
    return;
  }
  // z == 4
  if (bid < 256) {   // rope table
    int i = bid * 256 + tid;
    int pos = i >> 5, f = i & 31;
    float inv = __expf(-(float)f * (9.210340371976184f / 32.0f));
    float ang = (float)pos * inv;
    rope_c[i] = cosf(ang);
    rope_s[i] = sinf(ang);
    return;
  }
  if (bid < 384) {   // chunk_we, chunk c = bid-256
    __shared__ float red[16][17];
    __shared__ float wgt[16];
    int c = bid - 256;
    int row = tid >> 4, seg = tid & 15;
    const float* hrow = hs + ((size_t)c * 16 + row) * HIDN;
    float p = 0.f;
    #pragma unroll 8
    for (int k = seg * 128; k < seg * 128 + 128; k += 4) {
      float4 hv = *(const float4*)&hrow[k];
      float4 wv = *(const float4*)&Wc[k];
      p += hv.x * wv.x + hv.y * wv.y + hv.z * wv.z + hv.w * wv.w;
    }
    red[row][seg] = p;
    __syncthreads();
    if (tid < 16) {
      float lg = 0.f;
      #pragma unroll
      for (int j = 0; j < 16; ++j) lg += red[tid][j];
      lg += bc[0];
      float m = lg;
      #pragma unroll
      for (int msk = 1; msk <= 8; msk <<= 1) m = fmaxf(m, __shfl_xor(m, msk));
      float ev = __expf(lg - m);
      float sum = ev;
      #pragma unroll
      for (int msk = 1; msk <= 8; msk <<= 1) sum += __shfl_xor(sum, msk);
      wgt[tid] = ev / sum;
    }
    __syncthreads();
    #pragma unroll
    for (int j = 0; j < 8; ++j) {
      int hb = tid + j * 256;
      float acc = 0.f;
      #pragma unroll
      for (int r = 0; r < 16; ++r)
        acc += wgt[r] * hs[((size_t)c * 16 + r) * HIDN + hb];
      entries_bf[(size_t)c * HIDN + hb] = f2bf(acc);
    }
    return;
  }
  if (bid < 896) {   // transpose_w
    int idx = bid - 384;
    int zw = idx >> 8, byw = (idx >> 6) & 3, bxw = idx & 63;
    const float* src = zw ? Wv : Wk;
    u16* dst = Wkv_t + (size_t)zw * HDIM * 2048;
    int k0 = bxw * 32, n0 = byw * 32;
    #pragma unroll
    for (int i = 0; i < 32; i += 8)
      tile[ty + i][tx] = src[(size_t)(k0 + ty + i) * HDIM + (n0 + tx)];
    __syncthreads();
    #pragma unroll
    for (int i = 0; i < 32; i += 8)
      dst[(size_t)(n0 + ty + i) * 2048 + (k0 + tx)] = f2bf(tile[tx][ty + i]);
  }
}

// ---------------- 256x256 GEMM for q/lk/lv (+ck/cv block 192, +Wo transpose 193-255)
__global__ __launch_bounds__(512, 2) void k_gemm256(
    const u16* __restrict__ A, const u16* __restrict__ Wt3,
    const u16* __restrict__ entries_bf, const u16* __restrict__ Wkv_t,
    const float* __restrict__ Wo, u16* __restrict__ Wt_o,
    const float* __restrict__ bq, const float* __restrict__ blk, const float* __restrict__ blv,
    const float* __restrict__ bk, const float* __restrict__ bv,
    const float* __restrict__ qn_w, const float* __restrict__ kn_w,
    const float* __restrict__ rc, const float* __restrict__ rs,
    u16* __restrict__ q_out, u16* __restrict__ lk_out, u16* __restrict__ lv_t,
    u16* __restrict__ ck_bf, u16* __restrict__ cv_t) {
  __shared__ __align__(16) u16 lds[65536];     // 128 KB: 2 x 64 KB
  __shared__ float psq[2][4][128];             // 4 KB
  int tid = threadIdx.x, lane = tid & 63;
  int wid = tid >> 6;
  int wr = wid >> 2, wc = wid & 3;             // 2 x 4 waves
  int lin = blockIdx.x;

  if (lin >= 193) {   // Wo transpose: 63 blocks x 66 tiles (co-resident, no tail)
    float* tile = (float*)lds;                 // reuse big LDS; [32][33] layout
    int idx = lin - 193;
    int tx = tid & 31, ty8 = tid >> 5;         // 512 thr: ty8 in [0,16)
    for (int j = 0; j < 66; ++j) {
      int t = idx * 66 + j;
      if (t < 4096) {
        int k0 = (t & 63) * 32, n0 = (t >> 6) * 32;
        tile[ty8 * 33 + tx]        = Wo[(size_t)(k0 + ty8) * HIDN + n0 + tx];
        tile[(ty8 + 16) * 33 + tx] = Wo[(size_t)(k0 + ty8 + 16) * HIDN + n0 + tx];
      }
      __syncthreads();
      if (t < 4096) {
        int k0 = (t & 63) * 32, n0 = (t >> 6) * 32;
        Wt_o[(size_t)(n0 + ty8) * HIDN + k0 + tx]        = f2bf(tile[tx * 33 + ty8]);
        Wt_o[(size_t)(n0 + ty8 + 16) * HIDN + k0 + tx]   = f2bf(tile[tx * 33 + ty8 + 16]);
      }
      __syncthreads();
    }
    return;
  }

  int row0, col0, mode;
  const u16 *Ag, *Bg;
  if (lin < 192) {
    int swz = (lin & 7) * 24 + (lin >> 3);     // XCD-chunked: XCD x gets swz [24x, 24x+24)
    mode = swz >> 6;
    int t = swz & 63;
    int q = t >> 4, u2 = t & 15;               // 4x4 quadrants
    row0 = ((q & 1) * 4 + (u2 >> 2)) * 256;
    col0 = ((q >> 1) * 4 + (u2 & 3)) * 256;
    Ag = A; Bg = Wt3 + (size_t)mode * HIDN * HIDN;
  } else {
    mode = 3; row0 = 0; col0 = 0;
    Ag = entries_bf; Bg = Wkv_t;
  }
  int rA = lane & 15, kg = lane >> 4;          // kg in [0,4)
  int srow = tid >> 3, sslot = tid & 7;
  int ssl = sslot ^ (srow & 7);                // inverse swizzle on SOURCE slot

  f32x4 acc[8][4];
  #pragma unroll
  for (int m = 0; m < 8; ++m)
    #pragma unroll
    for (int n = 0; n < 4; ++n) acc[m][n] = (f32x4){0.f, 0.f, 0.f, 0.f};

  auto stage = [&](int b, int i, int kt) {
    const u16* src = (i < 4) ? Ag : Bg;
    int rg = ((i < 4) ? row0 : col0) + ((i & 3) * 64) + srow;
    gl_lds16(&src[(size_t)rg * HIDN + kt * 64 + ssl * 8],
             &lds[b * 32768 + i * 4096 + tid * 8]);
  };
  auto rdA = [&](int b, int m, int ks) -> short8 {
    int r = wr * 128 + m * 16 + rA;
    int slot = (ks * 4 + kg) ^ (r & 7);
    return *(const short8*)&lds[b * 32768 + r * 64 + slot * 8];
  };
  auto rdB = [&](int b, int n, int ks) -> short8 {
    int r = wc * 64 + n * 16 + rA;
    int slot = (ks * 4 + kg) ^ (r & 7);
    return *(const short8*)&lds[b * 32768 + 16384 + r * 64 + slot * 8];
  };

  // prologue: tile 0 -> buf 0
  #pragma unroll
  for (int i = 0; i < 8; ++i) stage(0, i, 0);

  short8 Af[4], Bf[4][2];
  for (int u = 0; u < NKT; ++u) {
    int cur = u & 1;
    asm volatile("s_waitcnt vmcnt(0)" ::: "memory");
    __builtin_amdgcn_sched_barrier(0);
    __builtin_amdgcn_s_barrier();
    if (u + 1 < NKT) {
      #pragma unroll
      for (int i = 0; i < 8; ++i) stage(cur ^ 1, i, u + 1);
    }
    #pragma unroll
    for (int n = 0; n < 4; ++n) { Bf[n][0] = rdB(cur, n, 0); Bf[n][1] = rdB(cur, n, 1); }
    // sub-phase 1: A m0-3 ks0
    #pragma unroll
    for (int m = 0; m < 4; ++m) Af[m] = rdA(cur, m, 0);
    asm volatile("s_waitcnt lgkmcnt(0)" ::: "memory");
    __builtin_amdgcn_sched_barrier(0);
    __builtin_amdgcn_s_setprio(1);
    #pragma unroll
    for (int m = 0; m < 4; ++m)
      #pragma unroll
      for (int n = 0; n < 4; ++n)
        acc[m][n] = __builtin_amdgcn_mfma_f32_16x16x32_bf16(Af[m], Bf[n][0], acc[m][n], 0, 0, 0);
    __builtin_amdgcn_s_setprio(0);
    // sub-phase 2: A m0-3 ks1
    #pragma unroll
    for (int m = 0; m < 4; ++m) Af[m] = rdA(cur, m, 1);
    asm volatile("s_waitcnt lgkmcnt(0)" ::: "memory");
    __builtin_amdgcn_sched_barrier(0);
    __builtin_amdgcn_s_setprio(1);
    #pragma unroll
    for (int m = 0; m < 4; ++m)
      #pragma unroll
      for (int n = 0; n < 4; ++n)
        acc[m][n] = __builtin_amdgcn_mfma_f32_16x16x32_bf16(Af[m], Bf[n][1], acc[m][n], 0, 0, 0);
    __builtin_amdgcn_s_setprio(0);
    // sub-phase 3: A m4-7 ks0
    #pragma unroll
    for (int m = 0; m < 4; ++m) Af[m] = rdA(cur, m + 4, 0);
    asm volatile("s_waitcnt lgkmcnt(0)" ::: "memory");
    __builtin_amdgcn_sched_barrier(0);
    __builtin_amdgcn_s_setprio(1);
    #pragma unroll
    for (int m = 0; m < 4; ++m)
      #pragma unroll
      for (int n = 0; n < 4; ++n)
        acc[m + 4][n] = __builtin_amdgcn_mfma_f32_16x16x32_bf16(Af[m], Bf[n][0], acc[m + 4][n], 0, 0, 0);
    __builtin_amdgcn_s_setprio(0);
    // sub-phase 4: A m4-7 ks1
    #pragma unroll
    for (int m = 0; m < 4; ++m) Af[m] = rdA(cur, m + 4, 1);
    asm volatile("s_waitcnt lgkmcnt(0)" ::: "memory");
    __builtin_amdgcn_sched_barrier(0);
    __builtin_amdgcn_s_setprio(1);
    #pragma unroll
    for (int m = 0; m < 4; ++m)
      #pragma unroll
      for (int n = 0; n < 4; ++n)
        acc[m + 4][n] = __builtin_amdgcn_mfma_f32_16x16x32_bf16(Af[m], Bf[n][1], acc[m + 4][n], 0, 0, 0);
    __builtin_amdgcn_s_setprio(0);
  }

  // ---------------- epilogue
  int cl = rA, rbase = kg * 4;
  #pragma unroll
  for (int n = 0; n < 4; ++n) {
    int dl = wc * 64 + n * 16 + cl;
    float bb;
    if (mode == 3)      bb = (dl < 128) ? bk[dl] : bv[dl - 128];
    else if (mode == 0) bb = bq[col0 + dl];
    else if (mode == 1) bb = blk[col0 + dl];
    else                bb = blv[col0 + dl];
    #pragma unroll
    for (int m = 0; m < 8; ++m)
      #pragma unroll
      for (int j = 0; j < 4; ++j) acc[m][n][j] += bb;
  }

  if (mode == 2) {
    int hh = (col0 >> 7) + (wc >> 1);
    #pragma unroll
    for (int m = 0; m < 8; ++m) {
      int sb = row0 + wr * 128 + m * 16 + rbase;
      #pragma unroll
      for (int n = 0; n < 4; ++n) {
        int dl = (wc & 1) * 64 + n * 16 + cl;
        ushort4 o;
        o.x = f2bf(acc[m][n][0]);
        o.y = f2bf(acc[m][n][1]);
        o.z = f2bf(acc[m][n][2]);
        o.w = f2bf(acc[m][n][3]);
        *(ushort4*)&lv_t[((size_t)hh * HDIM + dl) * S_LEN + sb] = o;
      }
    }
    return;
  }

  bool is_cv = (mode == 3) && (wc >= 2);
  if (!is_cv) {
    #pragma unroll
    for (int m = 0; m < 8; ++m)
      #pragma unroll
      for (int j = 0; j < 4; ++j) {
        float s2 = acc[m][0][j] * acc[m][0][j] + acc[m][1][j] * acc[m][1][j]
                 + acc[m][2][j] * acc[m][2][j] + acc[m][3][j] * acc[m][3][j];
        s2 += __shfl_xor(s2, 1); s2 += __shfl_xor(s2, 2);
        s2 += __shfl_xor(s2, 4); s2 += __shfl_xor(s2, 8);
        if (cl == 0) psq[wr][wc][m * 16 + rbase + j] = s2;
      }
  }
  __syncthreads();
  if (is_cv) {
    if (wr == 0) {
      #pragma unroll
      for (int m = 0; m < 8; ++m) {
        int cchunk = m * 16 + rbase;
        #pragma unroll
        for (int n = 0; n < 4; ++n) {
          int d = (wc - 2) * 64 + n * 16 + cl;
          #pragma unroll
          for (int j = 0; j < 4; ++j)
            cv_t[(size_t)d * NCHNK + cchunk + j] = f2bf(acc[m][n][j]);
        }
      }
    }
    return;
  }
  {
    const float* nw = (mode == 0) ? qn_w : kn_w;
    int hgrp = wc >> 1;
    float nwv[4];
    #pragma unroll
    for (int n = 0; n < 4; ++n) nwv[n] = nw[(wc & 1) * 64 + n * 16 + cl];
    #pragma unroll
    for (int m = 0; m < 8; ++m)
      #pragma unroll
      for (int j = 0; j < 4; ++j) {
        int r16 = m * 16 + rbase + j;
        int s = row0 + wr * 128 + r16;
        bool valid = (mode != 3) || (s < NCHNK);
        int sc2 = valid ? s : 0;
        int pos = (mode == 3) ? (sc2 * 16 + 15) : sc2;
        float rr2 = rsqrtf((psq[wr][hgrp * 2][r16] + psq[wr][hgrp * 2 + 1][r16]) * (1.f / 128.f) + 1e-6f);
        float o[4];
        if ((wc & 1) == 0) {
          #pragma unroll
          for (int n = 0; n < 2; ++n) {
            int i = n * 16 + cl;
            float ca = rc[pos * 32 + i], sa = rs[pos * 32 + i];
            float y1 = acc[m][n][j] * rr2 * nwv[n];
            float y2 = acc[m][n + 2][j] * rr2 * nwv[n + 2];
            o[n] = y1 * ca - y2 * sa;
            o[n + 2] = y1 * sa + y2 * ca;
          }
        } else {
          #pragma unroll
          for (int n = 0; n < 4; ++n) o[n] = acc[m][n][j] * rr2 * nwv[n];
        }
        if (valid) {
          u16* dst;
          if (mode == 3) dst = ck_bf + (size_t)s * HDIM + (wc & 1) * 64;
          else {
            u16* dstb = (mode == 0) ? q_out : lk_out;
            dst = dstb + ((size_t)((col0 >> 7) + hgrp) * S_LEN + s) * HDIM + (wc & 1) * 64;
          }
          #pragma unroll
          for (int n = 0; n < 4; ++n) dst[n * 16 + cl] = f2bf(o[n]);
        }
      }
  }
}

// ---------------- out GEMM: pipelined 128^2, counted 1-deep, XCD swizzle
__global__ __launch_bounds__(256, 2) void k_gemm_out(const u16* __restrict__ A, const u16* __restrict__ Bt,
                                                     const float* __restrict__ bias, float* __restrict__ C) {
  __shared__ __align__(16) u16 lds[32768];     // 64 KB: 2 x 32 KB
  int tid = threadIdx.x, lane = tid & 63;
  int wave = tid >> 6;
  int wr = wave >> 1, wc = wave & 1;
  int lin = blockIdx.x + (blockIdx.y << 4);
  int swz = (lin & 7) * 32 + (lin >> 3);       // bijective 256 = 8*32
  int row0 = (swz & 15) * 128, col0 = (swz >> 4) * 128;
  int rA = lane & 15, kg = lane >> 4;
  int srow = tid >> 3, sslot = tid & 7;        // srow in [0,32)
  int ssl = sslot ^ (srow & 7);

  f32x4 acc[4][4];
  #pragma unroll
  for (int m = 0; m < 4; ++m)
    #pragma unroll
    for (int n = 0; n < 4; ++n) acc[m][n] = (f32x4){0.f, 0.f, 0.f, 0.f};

  auto stage = [&](int b, int i, int kt) {
    const u16* src = (i < 4) ? Bt : A;
    int rg = ((i < 4) ? col0 : row0) + (i & 3) * 32 + srow;
    int dofs = (i < 4) ? (8192 + i * 2048) : ((i - 4) * 2048);
    gl_lds16(&src[(size_t)rg * HIDN + kt * 64 + ssl * 8],
             &lds[b * 16384 + dofs + tid * 8]);
  };
  auto rdA = [&](int b, int m, int ks) -> short8 {
    int r = wr * 64 + m * 16 + rA;
    int slot = (ks * 4 + kg) ^ (r & 7);
    return *(const short8*)&lds[b * 16384 + r * 64 + slot * 8];
  };
  auto rdB = [&](int b, int n, int ks) -> short8 {
    int r = wc * 64 + n * 16 + rA;
    int slot = (ks * 4 + kg) ^ (r & 7);
    return *(const short8*)&lds[b * 16384 + 8192 + r * 64 + slot * 8];
  };

  #pragma unroll
  for (int i = 0; i < 8; ++i) stage(0, i, 0);

  short8 Af[4], Bf[4][2];
  for (int u = 0; u < NKT; ++u) {
    int cur = u & 1;
    bool pf = (u + 1 < NKT);
    if (pf) {
      #pragma unroll
      for (int i = 0; i < 8; ++i) stage(cur ^ 1, i, u + 1);
    }
    if (pf) asm volatile("s_waitcnt vmcnt(8)" ::: "memory");
    else    asm volatile("s_waitcnt vmcnt(0)" ::: "memory");
    __builtin_amdgcn_sched_barrier(0);
    __builtin_amdgcn_s_barrier();
    #pragma unroll
    for (int n = 0; n < 4; ++n) { Bf[n][0] = rdB(cur, n, 0); Bf[n][1] = rdB(cur, n, 1); }
    #pragma unroll
    for (int m = 0; m < 4; ++m) Af[m] = rdA(cur, m, 0);
    asm volatile("s_waitcnt lgkmcnt(0)" ::: "memory");
    __builtin_amdgcn_sched_barrier(0);
    __builtin_amdgcn_s_setprio(1);
    #pragma unroll
    for (int m = 0; m < 4; ++m)
      #pragma unroll
      for (int n = 0; n < 4; ++n)
        acc[m][n] = __builtin_amdgcn_mfma_f32_16x16x32_bf16(Af[m], Bf[n][0], acc[m][n], 0, 0, 0);
    __builtin_amdgcn_s_setprio(0);
    #pragma unroll
    for (int m = 0; m < 4; ++m) Af[m] = rdA(cur, m, 1);
    asm volatile("s_waitcnt lgkmcnt(0)" ::: "memory");
    __builtin_amdgcn_sched_barrier(0);
    __builtin_amdgcn_s_setprio(1);
    #pragma unroll
    for (int m = 0; m < 4; ++m)
      #pragma unroll
      for (int n = 0; n < 4; ++n)
        acc[m][n] = __builtin_amdgcn_mfma_f32_16x16x32_bf16(Af[m], Bf[n][1], acc[m][n], 0, 0, 0);
    __builtin_amdgcn_s_setprio(0);
    __builtin_amdgcn_s_barrier();
  }

  int rbase = kg * 4, cl = rA;
  #pragma unroll
  for (int m = 0; m < 4; ++m) {
    int rowb = row0 + wr * 64 + m * 16 + rbase;
    #pragma unroll
    for (int n = 0; n < 4; ++n) {
      int col = col0 + wc * 64 + n * 16 + cl;
      float bb = bias[col];
      #pragma unroll
      for (int j = 0; j < 4; ++j)
        C[(size_t)(rowb + j) * HIDN + col] = acc[m][n][j] + bb;
    }
  }
}

// ---------------- merged attention with T14 async V staging
__global__ __launch_bounds__(256) void k_attn(const u16* __restrict__ q_bf, const u16* __restrict__ ck_bf,
                                              const u16* __restrict__ cv_t, const float* __restrict__ sink_k,
                                              const float* __restrict__ sink_v,
                                              const u16* __restrict__ lk_bf, const u16* __restrict__ lv_t,
                                              u16* __restrict__ merged) {
  __shared__ __align__(16) u16 kv[21760];
  __shared__ __align__(16) float sc[32][164];
  __shared__ __align__(16) u16 pb[32][168];
  int tid = threadIdx.x, lane = tid & 63, wave = tid >> 6;
  int lin = blockIdx.x;
  int sw = (lin & 7) * 128 + (lin >> 3);
  int s0 = (sw & 63) * 32, h = sw >> 6;
  const size_t hb = (size_t)h * S_LEN * HDIM;
  int rA = lane & 15, kg8 = (lane >> 4) * 8;
  int qt = wave & 1, wg = wave >> 1;

  short8 aq[4];
  #pragma unroll
  for (int c = 0; c < 4; ++c)
    aq[c] = *(const short8*)&q_bf[hb + (size_t)(s0 + qt * 16 + rA) * HDIM + c * 32 + kg8];

  // ======== compressed phase ========
  int cmax = s0 / 16 + 2; if (cmax > 128) cmax = 128;
  int nkeys = cmax + 1;
  int nkt = (nkeys + 15) >> 4, nkc = (nkeys + 31) >> 5;

  // T14: issue cv_t loads into registers EARLY (predicated static unroll)
  int dV = tid & 127, halfV = tid >> 7;
  int ng = cmax >> 3;
  const u16* cvrow = cv_t + (size_t)dV * NCHNK;
  uint4 vv[8];
  #pragma unroll
  for (int i = 0; i < 8; ++i) {
    int g = halfV + 2 * i;
    vv[i] = make_uint4(0, 0, 0, 0);
    if (g < ng) vv[i] = *(const uint4*)&cvrow[g * 8];
  }
  float svf = sink_v[h * HDIM + dV];

  for (int i = tid; i < cmax * 16; i += 256) {
    int r = i >> 4, cz = (i & 15) * 8;
    *(uint4*)&kv[r * 136 + cz] = *(const uint4*)&ck_bf[r * HDIM + cz];
  }
  if (tid < 128) kv[cmax * 136 + tid] = f2bf(sink_k[h * HDIM + tid]);
  __syncthreads();

  for (int kt = wg; kt < nkt; kt += 2) {
    f32x4 a = (f32x4){0.f, 0.f, 0.f, 0.f};
    #pragma unroll
    for (int c = 0; c < 4; ++c) {
      short8 bk2 = *(const short8*)&kv[(kt * 16 + rA) * 136 + c * 32 + kg8];
      a = __builtin_amdgcn_mfma_f32_16x16x32_bf16(aq[c], bk2, a, 0, 0, 0);
    }
    int rq = qt * 16 + (lane >> 4) * 4;
    #pragma unroll
    for (int j = 0; j < 4; ++j) sc[rq + j][kt * 16 + rA] = a[j];
  }
  __syncthreads();

  { // softmax (8 lanes / row)
    int ql = tid >> 3, e = tid & 7, s = s0 + ql;
    int NK = nkc * 32;
    float m = -1e30f;
    for (int i = e; i < NK; i += 8) {
      if (i < nkeys) {
        float raw = sc[ql][i];
        bool valid = (i < cmax) ? (i * 16 + 15 <= s) : true;
        float v = valid ? raw * SCALE : -1e9f;
        sc[ql][i] = v;
        m = fmaxf(m, v);
      }
    }
    m = fmaxf(m, __shfl_xor(m, 1));
    m = fmaxf(m, __shfl_xor(m, 2));
    m = fmaxf(m, __shfl_xor(m, 4));
    float sum = 0.f;
    for (int i = e; i < NK; i += 8) {
      if (i < nkeys) {
        float pv = __expf(sc[ql][i] - m);
        sc[ql][i] = pv;
        sum += pv;
      }
    }
    sum += __shfl_xor(sum, 1);
    sum += __shfl_xor(sum, 2);
    sum += __shfl_xor(sum, 4);
    float inv = 1.f / sum;
    for (int i = e; i < NK; i += 8)
      pb[ql][i] = (i < nkeys) ? f2bf(sc[ql][i] * inv) : (u16)0;
  }
  __syncthreads();

  { // write V^T from pre-issued registers + scalar tail
    #pragma unroll
    for (int i = 0; i < 8; ++i) {
      int g = halfV + 2 * i;
      if (g < ng) *(uint4*)&kv[dV * 168 + g * 8] = vv[i];
    }
    u16 sv = f2bf(svf);
    int NC = nkc * 32;
    for (int c = ng * 8 + halfV; c < NC; c += 2) {
      u16 v = (c < cmax) ? cvrow[c] : ((c == cmax) ? sv : (u16)0);
      kv[dV * 168 + c] = v;
    }
  }
  __syncthreads();

  f32x4 po_c[4];
  #pragma unroll
  for (int n = 0; n < 4; ++n) po_c[n] = (f32x4){0.f, 0.f, 0.f, 0.f};
  for (int kc = 0; kc < nkc; ++kc) {
    short8 pfrag = *(const short8*)&pb[qt * 16 + rA][kc * 32 + kg8];
    #pragma unroll
    for (int n = 0; n < 4; ++n) {
      short8 av = *(const short8*)&kv[(wg * 64 + n * 16 + rA) * 168 + kc * 32 + kg8];
      po_c[n] = __builtin_amdgcn_mfma_f32_16x16x32_bf16(av, pfrag, po_c[n], 0, 0, 0);
    }
  }
  __syncthreads();

  // ======== local phase ========
  int tbase = s0 - 128;
  // T14: issue lv_t loads into registers while staging K
  uint4 lvv[10];
  {
    const size_t hbt = (size_t)h * HDIM * S_LEN;
    #pragma unroll
    for (int i = 0; i < 10; ++i) {
      int c8 = halfV + 2 * i;
      int t0 = tbase + c8 * 8;
      lvv[i] = make_uint4(0, 0, 0, 0);
      if (t0 >= 0) lvv[i] = *(const uint4*)&lv_t[hbt + (size_t)dV * S_LEN + t0];
    }
  }
  for (int i = tid; i < 160 * 16; i += 256) {
    int r = i >> 4, cz = (i & 15) * 8;
    int t = tbase + r;
    uint4 val = make_uint4(0, 0, 0, 0);
    if (t >= 0) val = *(const uint4*)&lk_bf[hb + (size_t)t * HDIM + cz];
    *(uint4*)&kv[r * 136 + cz] = val;
  }
  __syncthreads();

  for (int kt = wg; kt < 10; kt += 2) {
    f32x4 a = (f32x4){0.f, 0.f, 0.f, 0.f};
    #pragma unroll
    for (int c = 0; c < 4; ++c) {
      short8 bk2 = *(const short8*)&kv[(kt * 16 + rA) * 136 + c * 32 + kg8];
      a = __builtin_amdgcn_mfma_f32_16x16x32_bf16(aq[c], bk2, a, 0, 0, 0);
    }
    int rq = qt * 16 + (lane >> 4) * 4;
    #pragma unroll
    for (int j = 0; j < 4; ++j) sc[rq + j][kt * 16 + rA] = a[j];
  }
  __syncthreads();

  {
    int ql = tid >> 3, e = tid & 7;
    int ilo = 128 - s0; if (ql > ilo) ilo = ql;
    int ihi = ql + 128;
    float m = -1e30f;
    for (int i = e; i < 160; i += 8) {
      bool valid = (i >= ilo) && (i <= ihi);
      float v = valid ? sc[ql][i] * SCALE : -1e9f;
      sc[ql][i] = v;
      m = fmaxf(m, v);
    }
    m = fmaxf(m, __shfl_xor(m, 1));
    m = fmaxf(m, __shfl_xor(m, 2));
    m = fmaxf(m, __shfl_xor(m, 4));
    float sum = 0.f;
    for (int i = e; i < 160; i += 8) {
      float pv = __expf(sc[ql][i] - m);
      sc[ql][i] = pv;
      sum += pv;
    }
    sum += __shfl_xor(sum, 1);
    sum += __shfl_xor(sum, 2);
    sum += __shfl_xor(sum, 4);
    float inv = 1.f / sum;
    for (int i = e; i < 160; i += 8) pb[ql][i] = f2bf(sc[ql][i] * inv);
  }
  __syncthreads();

  { // write V^T from pre-issued registers
    #pragma unroll
    for (int i = 0; i < 10; ++i) {
      int c8 = halfV + 2 * i;
      *(uint4*)&kv[dV * 168 + c8 * 8] = lvv[i];
    }
  }
  __syncthreads();

  {
    f32x4 po[4];
    #pragma unroll
    for (int n = 0; n < 4; ++n) po[n] = (f32x4){0.f, 0.f, 0.f, 0.f};
    #pragma unroll
    for (int kc = 0; kc < 5; ++kc) {
      short8 pfrag = *(const short8*)&pb[qt * 16 + rA][kc * 32 + kg8];
      #pragma unroll
      for (int n = 0; n < 4; ++n) {
        short8 av = *(const short8*)&kv[(wg * 64 + n * 16 + rA) * 168 + kc * 32 + kg8];
        po[n] = __builtin_amdgcn_mfma_f32_16x16x32_bf16(av, pfrag, po[n], 0, 0, 0);
      }
    }
    int q = qt * 16 + rA;
    int s = s0 + q;
    int rb = (lane >> 4) * 4;
    #pragma unroll
    for (int n = 0; n < 4; ++n) {
      int d0 = wg * 64 + n * 16 + rb;
      ushort4 o;
      o.x = f2bf(0.5f * (po[n][0] + po_c[n][0]));
      o.y = f2bf(0.5f * (po[n][1] + po_c[n][1]));
      o.z = f2bf(0.5f * (po[n][2] + po_c[n][2]));
      o.w = f2bf(0.5f * (po[n][3] + po_c[n][3]));
      *(ushort4*)&merged[(size_t)s * HIDN + h * HDIM + d0] = o;
    }
  }
}

extern "C" void kernel_launch(void* const* d_in, const int* in_sizes, int n_in,
                              void* d_out, int out_size, void* d_ws, size_t ws_size,
                              hipStream_t stream) {
  const float* hs     = (const float*)d_in[0];
  const float* Wq     = (const float*)d_in[1];
  const float* bq     = (const float*)d_in[2];
  const float* Wc     = (const float*)d_in[3];
  const float* bc     = (const float*)d_in[4];
  const float* Wk     = (const float*)d_in[5];
  const float* bk     = (const float*)d_in[6];
  const float* Wv     = (const float*)d_in[7];
  const float* bv     = (const float*)d_in[8];
  const float* Wlk    = (const float*)d_in[9];
  const float* blk    = (const float*)d_in[10];
  const float* Wlv    = (const float*)d_in[11];
  const float* blv    = (const float*)d_in[12];
  const float* qn_w   = (const float*)d_in[13];
  const float* kn_w   = (const float*)d_in[14];
  const float* sink_k = (const float*)d_in[15];
  const float* sink_v = (const float*)d_in[16];
  const float* Wo     = (const float*)d_in[17];
  const float* bo     = (const float*)d_in[18];
  float* out = (float*)d_out;

  char* p = (char*)d_ws;
  auto alloc = [&](size_t bytes) {
    char* r = p;
    p += (bytes + 255) & ~(size_t)255;
    return r;
  };
  float* rope_c  = (float*)alloc((size_t)S_LEN * 32 * 4);
  float* rope_s  = (float*)alloc((size_t)S_LEN * 32 * 4);
  u16*   hs_bf   = (u16*)  alloc((size_t)S_LEN * HIDN * 2);
  u16*   Wt3     = (u16*)  alloc((size_t)3 * HIDN * HIDN * 2);
  u16*   Wt_o    = (u16*)  alloc((size_t)HIDN * HIDN * 2);
  u16*   Wkv_t   = (u16*)  alloc((size_t)2 * HDIM * HIDN * 2);
  u16*   ent_bf  = (u16*)  alloc((size_t)256 * HIDN * 2);
  u16*   q_bf    = (u16*)  alloc((size_t)NHEAD * S_LEN * HDIM * 2);
  u16*   lk_bf   = (u16*)  alloc((size_t)NHEAD * S_LEN * HDIM * 2);
  u16*   lv_t    = (u16*)  alloc((size_t)NHEAD * HDIM * S_LEN * 2);
  u16*   ck_bf   = (u16*)  alloc((size_t)NCHNK * HDIM * 2);
  u16*   cv_t    = (u16*)  alloc((size_t)HDIM * NCHNK * 2);
  u16*   merged  = (u16*)  alloc((size_t)S_LEN * HIDN * 2);
  (void)ws_size; (void)in_sizes; (void)n_in; (void)out_size;

  // preprocessing (Wo transpose moved into k_gemm256)
  k_pre<<<dim3(64, 64, 5), dim3(32, 8), 0, stream>>>(Wq, Wlk, Wlv, hs, Wc, bc, Wk, Wv,
                                                     Wt3, hs_bf, rope_c, rope_s,
                                                     ent_bf, Wkv_t);

  // fused q/lk/lv + ck/cv projections + Wo transpose on the 63 idle CUs
  k_gemm256<<<256, 512, 0, stream>>>(hs_bf, Wt3, ent_bf, Wkv_t, Wo, Wt_o,
                                     bq, blk, blv, bk, bv, qn_w, kn_w,
                                     rope_c, rope_s, q_bf, lk_bf, lv_t, ck_bf, cv_t);

  // merged attention (compressed + local + merge), XCD-chunked, async V staging
  k_attn<<<1024, 256, 0, stream>>>(q_bf, ck_bf, cv_t, sink_k, sink_v,
                                   lk_bf, lv_t, merged);

  // output projection (pipelined 128^2)
  k_gemm_out<<<dim3(16, 16), 256, 0, stream>>>(merged, Wt_o, bo, out);
}